// Round 1
// baseline (774.301 us; speedup 1.0000x reference)
//
#include <hip/hip_runtime.h>
#include <hip/hip_bf16.h>

typedef __attribute__((ext_vector_type(8))) short bf16x8;
typedef __attribute__((ext_vector_type(4))) float f32x4;

#define MFMA16(a, b, c) __builtin_amdgcn_mfma_f32_16x16x32_bf16((a), (b), (c), 0, 0, 0)

__device__ __forceinline__ ushort f2bf(float f) {
    unsigned int x = __float_as_uint(f);
    x += 0x7fffu + ((x >> 16) & 1u);
    return (ushort)(x >> 16);
}
__device__ __forceinline__ float bf2f(ushort u) {
    return __uint_as_float(((unsigned int)u) << 16);
}

__device__ __forceinline__ float rmax16(float v) {
    v = fmaxf(v, __shfl_xor(v, 1));
    v = fmaxf(v, __shfl_xor(v, 2));
    v = fmaxf(v, __shfl_xor(v, 4));
    v = fmaxf(v, __shfl_xor(v, 8));
    return v;
}
__device__ __forceinline__ float rsum16(float v) {
    v += __shfl_xor(v, 1);
    v += __shfl_xor(v, 2);
    v += __shfl_xor(v, 4);
    v += __shfl_xor(v, 8);
    return v;
}

// ---------------- f32 -> bf16 flat convert (n4 = n/4 float4 groups) ----------------
__global__ void cvt_f32_bf16_k(const float* __restrict__ in, ushort* __restrict__ out, int n4) {
    int i = blockIdx.x * blockDim.x + threadIdx.x;
    if (i >= n4) return;
    float4 v = ((const float4*)in)[i];
    ushort4 u;
    u.x = f2bf(v.x); u.y = f2bf(v.y); u.z = f2bf(v.z); u.w = f2bf(v.w);
    ((ushort4*)out)[i] = u;
}

// ---------------- transpose + convert: in f32 [R][C] -> out bf16 [C][R] ----------------
__global__ __launch_bounds__(256) void tpc_f32_bf16_k(const float* __restrict__ in, ushort* __restrict__ out,
                                                      int R, int C) {
    __shared__ ushort t[32][33];
    const int c0 = blockIdx.x * 32, r0 = blockIdx.y * 32;
    const int lx = threadIdx.x & 31, ly = threadIdx.x >> 5;
#pragma unroll
    for (int i = 0; i < 4; ++i)
        t[ly + i * 8][lx] = f2bf(in[(size_t)(r0 + ly + i * 8) * C + c0 + lx]);
    __syncthreads();
#pragma unroll
    for (int i = 0; i < 4; ++i)
        out[(size_t)(c0 + ly + i * 8) * R + r0 + lx] = t[lx][ly + i * 8];
}

// ---------------- transpose bf16: in [R][C] -> out [C][R] ----------------
__global__ __launch_bounds__(256) void tp_bf16_k(const ushort* __restrict__ in, ushort* __restrict__ out,
                                                 int R, int C) {
    __shared__ ushort t[32][33];
    const int c0 = blockIdx.x * 32, r0 = blockIdx.y * 32;
    const int lx = threadIdx.x & 31, ly = threadIdx.x >> 5;
#pragma unroll
    for (int i = 0; i < 4; ++i)
        t[ly + i * 8][lx] = in[(size_t)(r0 + ly + i * 8) * C + c0 + lx];
    __syncthreads();
#pragma unroll
    for (int i = 0; i < 4; ++i)
        out[(size_t)(c0 + ly + i * 8) * R + r0 + lx] = t[lx][ly + i * 8];
}

// ---------------- in-place RoPE on bf16 [S][NH*128] ----------------
__global__ void rope_k(ushort* __restrict__ t, const float* __restrict__ cs, const float* __restrict__ sn, int NH) {
    int i = blockIdx.x * blockDim.x + threadIdx.x;  // over S*NH*64
    int d = i & 63;
    int rest = i >> 6;
    int s = rest / NH;
    int h = rest - s * NH;
    size_t base = ((size_t)s * NH + h) * 128;
    float t0 = bf2f(t[base + d]);
    float t1 = bf2f(t[base + d + 64]);
    float cA = cs[s * 128 + d], cB = cs[s * 128 + d + 64];
    float sA = sn[s * 128 + d], sB = sn[s * 128 + d + 64];
    t[base + d] = f2bf(t0 * cA - t1 * sA);
    t[base + d + 64] = f2bf(t1 * cB + t0 * sB);
}

// ---------------- bf16 GEMM: C[M][N] = A[M][K] @ Bt[N][K]^T ----------------
// 128x128 tile, BK=32, 4 waves (2x2), each wave 64x64 via 4x4 16x16x32 MFMAs.
__global__ __launch_bounds__(256) void gemm_bf16_k(const ushort* __restrict__ A, const ushort* __restrict__ Bt,
                                                   void* __restrict__ C, int M, int N, int K, int cbf) {
    __shared__ ushort As[128 * 40];
    __shared__ ushort Bs[128 * 40];
    const int tid = threadIdx.x;
    const int m0 = blockIdx.x * 128, n0 = blockIdx.y * 128;
    const int lane = tid & 63, wid = tid >> 6;
    const int wr = wid >> 1, wc = wid & 1;
    const int l15 = lane & 15, lhi = lane >> 4;
    const int srow = tid >> 1, soff = (tid & 1) * 16;

    f32x4 acc[4][4];
#pragma unroll
    for (int m = 0; m < 4; ++m)
#pragma unroll
        for (int n = 0; n < 4; ++n) acc[m][n] = (f32x4){0.f, 0.f, 0.f, 0.f};

    const ushort* ga = A + (size_t)(m0 + srow) * K + soff;
    const ushort* gb = Bt + (size_t)(n0 + srow) * K + soff;
    ushort* wa = &As[srow * 40 + soff];
    ushort* wb = &Bs[srow * 40 + soff];

    for (int k0 = 0; k0 < K; k0 += 32) {
        bf16x8 a0 = *(const bf16x8*)(ga + k0);
        bf16x8 a1 = *(const bf16x8*)(ga + k0 + 8);
        bf16x8 b0 = *(const bf16x8*)(gb + k0);
        bf16x8 b1 = *(const bf16x8*)(gb + k0 + 8);
        __syncthreads();
        *(bf16x8*)(wa) = a0;
        *(bf16x8*)(wa + 8) = a1;
        *(bf16x8*)(wb) = b0;
        *(bf16x8*)(wb + 8) = b1;
        __syncthreads();
        bf16x8 af[4], bfr[4];
#pragma unroll
        for (int m = 0; m < 4; ++m)
            af[m] = *(const bf16x8*)&As[(wr * 64 + m * 16 + l15) * 40 + lhi * 8];
#pragma unroll
        for (int n = 0; n < 4; ++n)
            bfr[n] = *(const bf16x8*)&Bs[(wc * 64 + n * 16 + l15) * 40 + lhi * 8];
#pragma unroll
        for (int m = 0; m < 4; ++m)
#pragma unroll
            for (int n = 0; n < 4; ++n)
                acc[m][n] = MFMA16(af[m], bfr[n], acc[m][n]);
    }

#pragma unroll
    for (int m = 0; m < 4; ++m) {
        const int rb = m0 + wr * 64 + m * 16 + lhi * 4;
#pragma unroll
        for (int n = 0; n < 4; ++n) {
            const int col = n0 + wc * 64 + n * 16 + l15;
#pragma unroll
            for (int r = 0; r < 4; ++r) {
                if (cbf)
                    ((ushort*)C)[(size_t)(rb + r) * N + col] = f2bf(acc[m][n][r]);
                else
                    ((float*)C)[(size_t)(rb + r) * N + col] = acc[m][n][r];
            }
        }
    }
}

// ---------------- differential MQA attention ----------------
// One wave (64 thr) per (head, 16-row q strip). Two-pass flash:
// pass 1: online (m,l) for s1 and s2; pass 2: recompute scores, p = max(2*(a1-0.5*a2),0), PV.
__global__ __launch_bounds__(64) void attn_k(const ushort* __restrict__ q1b, const ushort* __restrict__ q2b,
                                             const ushort* __restrict__ kb, const ushort* __restrict__ vtb,
                                             ushort* __restrict__ aob) {
    const int h = blockIdx.x >> 7;
    const int strip = 127 - (blockIdx.x & 127);  // long strips dispatched first
    const int q0 = strip << 4;
    const int lane = threadIdx.x;
    const int l15 = lane & 15;
    const int lhi = lane >> 4;
    const float scale = 0.08838834764831845f;  // 1/sqrt(128)

    bf16x8 q1f[4], q2f[4];
    {
        size_t base = (size_t)(q0 + l15) * 2048 + h * 128 + lhi * 8;
#pragma unroll
        for (int c = 0; c < 4; ++c) {
            q1f[c] = *(const bf16x8*)(q1b + base + c * 32);
            q2f[c] = *(const bf16x8*)(q2b + base + c * 32);
        }
    }

    float m1[4], l1[4], m2[4], l2[4];
#pragma unroll
    for (int r = 0; r < 4; ++r) {
        m1[r] = -3.0e38f;
        m2[r] = -3.0e38f;
        l1[r] = 0.f;
        l2[r] = 0.f;
    }

    const int nchunk = (strip >> 1) + 1;  // ceil((strip+1)/2) 32-wide chunks

    // ---- pass 1: stats ----
    for (int ch = 0; ch < nchunk; ++ch) {
        const int kc = ch << 5;
        f32x4 s1[2], s2[2];
#pragma unroll
        for (int n2 = 0; n2 < 2; ++n2) {
            s1[n2] = (f32x4){0.f, 0.f, 0.f, 0.f};
            s2[n2] = (f32x4){0.f, 0.f, 0.f, 0.f};
            size_t krow = (size_t)(kc + n2 * 16 + l15) * 128 + lhi * 8;
#pragma unroll
            for (int c = 0; c < 4; ++c) {
                bf16x8 kf = *(const bf16x8*)(kb + krow + c * 32);
                s1[n2] = MFMA16(q1f[c], kf, s1[n2]);
                s2[n2] = MFMA16(q2f[c], kf, s2[n2]);
            }
        }
        const int c0 = kc + l15, c1 = kc + 16 + l15;
#pragma unroll
        for (int r = 0; r < 4; ++r) {
            const int row = q0 + lhi * 4 + r;
            float a0 = (c0 <= row) ? s1[0][r] * scale : -1e30f;
            float a1 = (c1 <= row) ? s1[1][r] * scale : -1e30f;
            float b0 = (c0 <= row) ? s2[0][r] * scale : -1e30f;
            float b1 = (c1 <= row) ? s2[1][r] * scale : -1e30f;
            float tm = rmax16(fmaxf(a0, a1));
            float mn = fmaxf(m1[r], tm);
            float ts = rsum16(expf(a0 - mn) + expf(a1 - mn));
            l1[r] = l1[r] * expf(m1[r] - mn) + ts;
            m1[r] = mn;
            tm = rmax16(fmaxf(b0, b1));
            mn = fmaxf(m2[r], tm);
            ts = rsum16(expf(b0 - mn) + expf(b1 - mn));
            l2[r] = l2[r] * expf(m2[r] - mn) + ts;
            m2[r] = mn;
        }
    }

    // per-row constants: a = (a1 - 0.5*a2) / (0.5 + 1e-8), a1 = exp(s1-m1)/l1
    const float inv_denom = 1.0f / (0.5f + 1e-8f);
    float c1f[4], c2f[4];
#pragma unroll
    for (int r = 0; r < 4; ++r) {
        c1f[r] = inv_denom / l1[r];
        c2f[r] = 0.5f * inv_denom / l2[r];
    }

    __shared__ ushort P[16][40];
    f32x4 o[8];
#pragma unroll
    for (int dt = 0; dt < 8; ++dt) o[dt] = (f32x4){0.f, 0.f, 0.f, 0.f};

    // ---- pass 2: probabilities + PV ----
    for (int ch = 0; ch < nchunk; ++ch) {
        const int kc = ch << 5;
#pragma unroll
        for (int n2 = 0; n2 < 2; ++n2) {
            f32x4 s1 = (f32x4){0.f, 0.f, 0.f, 0.f}, s2 = (f32x4){0.f, 0.f, 0.f, 0.f};
            size_t krow = (size_t)(kc + n2 * 16 + l15) * 128 + lhi * 8;
#pragma unroll
            for (int c = 0; c < 4; ++c) {
                bf16x8 kf = *(const bf16x8*)(kb + krow + c * 32);
                s1 = MFMA16(q1f[c], kf, s1);
                s2 = MFMA16(q2f[c], kf, s2);
            }
            const int col = kc + n2 * 16 + l15;
#pragma unroll
            for (int r = 0; r < 4; ++r) {
                const int row = q0 + lhi * 4 + r;
                float p = 0.f;
                if (col <= row) {
                    float e1 = expf(s1[r] * scale - m1[r]) * c1f[r];
                    float e2 = expf(s2[r] * scale - m2[r]) * c2f[r];
                    p = fmaxf(e1 - e2, 0.f);
                }
                P[lhi * 4 + r][n2 * 16 + l15] = f2bf(p);
            }
        }
        __syncthreads();
        bf16x8 pf = *(const bf16x8*)&P[l15][lhi * 8];
#pragma unroll
        for (int dt = 0; dt < 8; ++dt) {
            bf16x8 vf = *(const bf16x8*)(vtb + (size_t)(dt * 16 + l15) * 2048 + kc + lhi * 8);
            o[dt] = MFMA16(pf, vf, o[dt]);
        }
        __syncthreads();
    }

#pragma unroll
    for (int dt = 0; dt < 8; ++dt)
#pragma unroll
        for (int r = 0; r < 4; ++r)
            aob[(size_t)(q0 + lhi * 4 + r) * 2048 + h * 128 + dt * 16 + l15] = f2bf(o[dt][r]);
}

extern "C" void kernel_launch(void* const* d_in, const int* in_sizes, int n_in,
                              void* d_out, int out_size, void* d_ws, size_t ws_size,
                              hipStream_t stream) {
    const int S = 2048, HID = 2048, QD = 2048, HD = 128;

    const float* x = (const float*)d_in[0];
    const float* fcos = (const float*)d_in[1];
    const float* fsin = (const float*)d_in[2];
    // d_in[3] = mask (causal, implicit)
    const float* q1w = (const float*)d_in[4];
    const float* q2w = (const float*)d_in[5];
    const float* kw = (const float*)d_in[6];
    const float* vw = (const float*)d_in[7];
    const float* ow = (const float*)d_in[8];

    char* w = (char*)d_ws;
    ushort* xb = (ushort*)w;   w += (size_t)S * HID * 2;       // 8 MB
    ushort* w1t = (ushort*)w;  w += (size_t)QD * HID * 2;      // 8 MB
    ushort* w2t = (ushort*)w;  w += (size_t)QD * HID * 2;      // 8 MB
    ushort* wot = (ushort*)w;  w += (size_t)HID * QD * 2;      // 8 MB
    ushort* wkt = (ushort*)w;  w += (size_t)HD * HID * 2;      // 0.5 MB
    ushort* wvt = (ushort*)w;  w += (size_t)HD * HID * 2;      // 0.5 MB
    ushort* q1b = (ushort*)w;  w += (size_t)S * QD * 2;        // 8 MB
    ushort* q2b = (ushort*)w;  w += (size_t)S * QD * 2;        // 8 MB
    ushort* kbx = (ushort*)w;  w += (size_t)S * HD * 2;        // 0.5 MB
    ushort* vb = (ushort*)w;   w += (size_t)S * HD * 2;        // 0.5 MB
    ushort* vtb = (ushort*)w;  w += (size_t)HD * S * 2;        // 0.5 MB
    ushort* aob = (ushort*)w;  w += (size_t)S * QD * 2;        // 8 MB

    // 1. convert x -> bf16
    cvt_f32_bf16_k<<<dim3((S * HID / 4 + 255) / 256), dim3(256), 0, stream>>>(x, xb, S * HID / 4);

    // 2. transpose+convert weights -> [N][K] bf16
    tpc_f32_bf16_k<<<dim3(QD / 32, HID / 32), dim3(256), 0, stream>>>(q1w, w1t, HID, QD);
    tpc_f32_bf16_k<<<dim3(QD / 32, HID / 32), dim3(256), 0, stream>>>(q2w, w2t, HID, QD);
    tpc_f32_bf16_k<<<dim3(HD / 32, HID / 32), dim3(256), 0, stream>>>(kw, wkt, HID, HD);
    tpc_f32_bf16_k<<<dim3(HD / 32, HID / 32), dim3(256), 0, stream>>>(vw, wvt, HID, HD);
    tpc_f32_bf16_k<<<dim3(HID / 32, QD / 32), dim3(256), 0, stream>>>(ow, wot, QD, HID);

    // 3. projections (bf16 out)
    gemm_bf16_k<<<dim3(S / 128, QD / 128), dim3(256), 0, stream>>>(xb, w1t, q1b, S, QD, HID, 1);
    gemm_bf16_k<<<dim3(S / 128, QD / 128), dim3(256), 0, stream>>>(xb, w2t, q2b, S, QD, HID, 1);
    gemm_bf16_k<<<dim3(S / 128, HD / 128), dim3(256), 0, stream>>>(xb, wkt, kbx, S, HD, HID, 1);
    gemm_bf16_k<<<dim3(S / 128, HD / 128), dim3(256), 0, stream>>>(xb, wvt, vb, S, HD, HID, 1);

    // 4. RoPE in-place (q1, q2: 16 heads; k: 1 head)
    rope_k<<<dim3(S * 16 * 64 / 256), dim3(256), 0, stream>>>(q1b, fcos, fsin, 16);
    rope_k<<<dim3(S * 16 * 64 / 256), dim3(256), 0, stream>>>(q2b, fcos, fsin, 16);
    rope_k<<<dim3(S * 1 * 64 / 256), dim3(256), 0, stream>>>(kbx, fcos, fsin, 1);

    // 5. V -> Vt [128][2048]
    tp_bf16_k<<<dim3(HD / 32, S / 32), dim3(256), 0, stream>>>(vb, vtb, S, HD);

    // 6. attention
    attn_k<<<dim3(16 * 128), dim3(64), 0, stream>>>(q1b, q2b, kbx, vtb, aob);

    // 7. output projection (f32 out to d_out)
    gemm_bf16_k<<<dim3(S / 128, HID / 128), dim3(256), 0, stream>>>(aob, wot, (float*)d_out, S, HID, QD, 0);
}

// Round 2
// 510.232 us; speedup vs baseline: 1.5175x; 1.5175x over previous
//
#include <hip/hip_runtime.h>
#include <hip/hip_bf16.h>

typedef __attribute__((ext_vector_type(8))) short bf16x8;
typedef __attribute__((ext_vector_type(4))) float f32x4;

#define MFMA16(a, b, c) __builtin_amdgcn_mfma_f32_16x16x32_bf16((a), (b), (c), 0, 0, 0)

#define ATTN_SCALE 0.08838834764831845f  // 1/sqrt(128)

__device__ __forceinline__ ushort f2bf(float f) {
    unsigned int x = __float_as_uint(f);
    x += 0x7fffu + ((x >> 16) & 1u);
    return (ushort)(x >> 16);
}
__device__ __forceinline__ float bf2f(ushort u) {
    return __uint_as_float(((unsigned int)u) << 16);
}

// ---------------- f32 -> bf16 flat convert (n4 = n/4 float4 groups) ----------------
__global__ void cvt_f32_bf16_k(const float* __restrict__ in, ushort* __restrict__ out, int n4) {
    int i = blockIdx.x * blockDim.x + threadIdx.x;
    if (i >= n4) return;
    float4 v = ((const float4*)in)[i];
    ushort4 u;
    u.x = f2bf(v.x); u.y = f2bf(v.y); u.z = f2bf(v.z); u.w = f2bf(v.w);
    ((ushort4*)out)[i] = u;
}

// ---------------- transpose + convert: in f32 [R][C] -> out bf16 [C][R] ----------------
__global__ __launch_bounds__(256) void tpc_f32_bf16_k(const float* __restrict__ in, ushort* __restrict__ out,
                                                      int R, int C) {
    __shared__ ushort t[32][33];
    const int c0 = blockIdx.x * 32, r0 = blockIdx.y * 32;
    const int lx = threadIdx.x & 31, ly = threadIdx.x >> 5;
#pragma unroll
    for (int i = 0; i < 4; ++i)
        t[ly + i * 8][lx] = f2bf(in[(size_t)(r0 + ly + i * 8) * C + c0 + lx]);
    __syncthreads();
#pragma unroll
    for (int i = 0; i < 4; ++i)
        out[(size_t)(c0 + ly + i * 8) * R + r0 + lx] = t[lx][ly + i * 8];
}

// ---------------- transpose bf16: in [R][C] -> out [C][R] ----------------
__global__ __launch_bounds__(256) void tp_bf16_k(const ushort* __restrict__ in, ushort* __restrict__ out,
                                                 int R, int C) {
    __shared__ ushort t[32][33];
    const int c0 = blockIdx.x * 32, r0 = blockIdx.y * 32;
    const int lx = threadIdx.x & 31, ly = threadIdx.x >> 5;
#pragma unroll
    for (int i = 0; i < 4; ++i)
        t[ly + i * 8][lx] = in[(size_t)(r0 + ly + i * 8) * C + c0 + lx];
    __syncthreads();
#pragma unroll
    for (int i = 0; i < 4; ++i)
        out[(size_t)(c0 + ly + i * 8) * R + r0 + lx] = t[lx][ly + i * 8];
}

// ---------------- in-place RoPE on bf16 [S][NH*128] ----------------
__global__ void rope_k(ushort* __restrict__ t, const float* __restrict__ cs, const float* __restrict__ sn, int NH) {
    int i = blockIdx.x * blockDim.x + threadIdx.x;  // over S*NH*64
    int d = i & 63;
    int rest = i >> 6;
    int s = rest / NH;
    int h = rest - s * NH;
    size_t base = ((size_t)s * NH + h) * 128;
    float t0 = bf2f(t[base + d]);
    float t1 = bf2f(t[base + d + 64]);
    float cA = cs[s * 128 + d], cB = cs[s * 128 + d + 64];
    float sA = sn[s * 128 + d], sB = sn[s * 128 + d + 64];
    t[base + d] = f2bf(t0 * cA - t1 * sA);
    t[base + d + 64] = f2bf(t1 * cB + t0 * sB);
}

// ---------------- bf16 GEMM: C[M][N] = A[M][K] @ Bt[N][K]^T ----------------
// 128x128 tile, BK=32, 4 waves (2x2), each wave 64x64 via 4x4 16x16x32 MFMAs.
__global__ __launch_bounds__(256) void gemm_bf16_k(const ushort* __restrict__ A, const ushort* __restrict__ Bt,
                                                   void* __restrict__ C, int M, int N, int K, int cbf) {
    __shared__ ushort As[128 * 40];
    __shared__ ushort Bs[128 * 40];
    const int tid = threadIdx.x;
    const int m0 = blockIdx.x * 128, n0 = blockIdx.y * 128;
    const int lane = tid & 63, wid = tid >> 6;
    const int wr = wid >> 1, wc = wid & 1;
    const int l15 = lane & 15, lhi = lane >> 4;
    const int srow = tid >> 1, soff = (tid & 1) * 16;

    f32x4 acc[4][4];
#pragma unroll
    for (int m = 0; m < 4; ++m)
#pragma unroll
        for (int n = 0; n < 4; ++n) acc[m][n] = (f32x4){0.f, 0.f, 0.f, 0.f};

    const ushort* ga = A + (size_t)(m0 + srow) * K + soff;
    const ushort* gb = Bt + (size_t)(n0 + srow) * K + soff;
    ushort* wa = &As[srow * 40 + soff];
    ushort* wb = &Bs[srow * 40 + soff];

    for (int k0 = 0; k0 < K; k0 += 32) {
        bf16x8 a0 = *(const bf16x8*)(ga + k0);
        bf16x8 a1 = *(const bf16x8*)(ga + k0 + 8);
        bf16x8 b0 = *(const bf16x8*)(gb + k0);
        bf16x8 b1 = *(const bf16x8*)(gb + k0 + 8);
        __syncthreads();
        *(bf16x8*)(wa) = a0;
        *(bf16x8*)(wa + 8) = a1;
        *(bf16x8*)(wb) = b0;
        *(bf16x8*)(wb + 8) = b1;
        __syncthreads();
        bf16x8 af[4], bfr[4];
#pragma unroll
        for (int m = 0; m < 4; ++m)
            af[m] = *(const bf16x8*)&As[(wr * 64 + m * 16 + l15) * 40 + lhi * 8];
#pragma unroll
        for (int n = 0; n < 4; ++n)
            bfr[n] = *(const bf16x8*)&Bs[(wc * 64 + n * 16 + l15) * 40 + lhi * 8];
#pragma unroll
        for (int m = 0; m < 4; ++m)
#pragma unroll
            for (int n = 0; n < 4; ++n)
                acc[m][n] = MFMA16(af[m], bfr[n], acc[m][n]);
    }

#pragma unroll
    for (int m = 0; m < 4; ++m) {
        const int rb = m0 + wr * 64 + m * 16 + lhi * 4;
#pragma unroll
        for (int n = 0; n < 4; ++n) {
            const int col = n0 + wc * 64 + n * 16 + l15;
#pragma unroll
            for (int r = 0; r < 4; ++r) {
                if (cbf)
                    ((ushort*)C)[(size_t)(rb + r) * N + col] = f2bf(acc[m][n][r]);
                else
                    ((float*)C)[(size_t)(rb + r) * N + col] = acc[m][n][r];
            }
        }
    }
}

// ---------------- differential MQA attention ----------------
// Swapped-operand QK^T (mfma(K, Q)): each lane owns one q-row (col = l15), so
// the exp-sum is a lane-local scalar (no shuffles in the loop), and P re-layout
// for PV is 2x packed b64 LDS writes + 1 b128 read. No max-subtraction: scores
// are O(±6) so exp() is safe in f32, and the causal diagonal guarantees sum>=1.

template <bool MASKED>
__device__ __forceinline__ void pass1_chunk(int kc, int l15, int lhi, int qrow,
                                            const bf16x8* q1f, const bf16x8* q2f,
                                            const ushort* __restrict__ kb,
                                            float& sum1, float& sum2) {
    bf16x8 kf[2][4];
#pragma unroll
    for (int n2 = 0; n2 < 2; ++n2)
#pragma unroll
        for (int c = 0; c < 4; ++c)
            kf[n2][c] = *(const bf16x8*)(kb + (size_t)(kc + n2 * 16 + l15) * 128 + lhi * 8 + c * 32);
    f32x4 s1[2], s2[2];
#pragma unroll
    for (int n2 = 0; n2 < 2; ++n2) {
        s1[n2] = (f32x4){0.f, 0.f, 0.f, 0.f};
        s2[n2] = (f32x4){0.f, 0.f, 0.f, 0.f};
#pragma unroll
        for (int c = 0; c < 4; ++c) {
            s1[n2] = MFMA16(kf[n2][c], q1f[c], s1[n2]);
            s2[n2] = MFMA16(kf[n2][c], q2f[c], s2[n2]);
        }
    }
    const int kbase = kc + lhi * 4;
#pragma unroll
    for (int n2 = 0; n2 < 2; ++n2)
#pragma unroll
        for (int r = 0; r < 4; ++r) {
            float e1 = __expf(s1[n2][r] * ATTN_SCALE);
            float e2 = __expf(s2[n2][r] * ATTN_SCALE);
            if (MASKED) {
                bool ok = (kbase + n2 * 16 + r) <= qrow;
                e1 = ok ? e1 : 0.f;
                e2 = ok ? e2 : 0.f;
            }
            sum1 += e1;
            sum2 += e2;
        }
}

template <bool MASKED>
__device__ __forceinline__ void pass2_chunk(int kc, ushort* __restrict__ Pb,
                                            int l15, int lhi, int qrow,
                                            const bf16x8* q1f, const bf16x8* q2f,
                                            const ushort* __restrict__ kb,
                                            const ushort* __restrict__ vtb,
                                            float c1, float c2, f32x4* o) {
    bf16x8 vf[8];
#pragma unroll
    for (int dt = 0; dt < 8; ++dt)
        vf[dt] = *(const bf16x8*)(vtb + (size_t)(dt * 16 + l15) * 2048 + kc + lhi * 8);
    bf16x8 kf[2][4];
#pragma unroll
    for (int n2 = 0; n2 < 2; ++n2)
#pragma unroll
        for (int c = 0; c < 4; ++c)
            kf[n2][c] = *(const bf16x8*)(kb + (size_t)(kc + n2 * 16 + l15) * 128 + lhi * 8 + c * 32);
    f32x4 s1[2], s2[2];
#pragma unroll
    for (int n2 = 0; n2 < 2; ++n2) {
        s1[n2] = (f32x4){0.f, 0.f, 0.f, 0.f};
        s2[n2] = (f32x4){0.f, 0.f, 0.f, 0.f};
#pragma unroll
        for (int c = 0; c < 4; ++c) {
            s1[n2] = MFMA16(kf[n2][c], q1f[c], s1[n2]);
            s2[n2] = MFMA16(kf[n2][c], q2f[c], s2[n2]);
        }
    }
    const int kbase = kc + lhi * 4;
#pragma unroll
    for (int n2 = 0; n2 < 2; ++n2) {
        float p[4];
#pragma unroll
        for (int r = 0; r < 4; ++r) {
            float e1 = __expf(s1[n2][r] * ATTN_SCALE) * c1;
            float e2 = __expf(s2[n2][r] * ATTN_SCALE) * c2;
            float pv = fmaxf(e1 - e2, 0.f);
            if (MASKED) pv = ((kbase + n2 * 16 + r) <= qrow) ? pv : 0.f;
            p[r] = pv;
        }
        uint2 w;
        w.x = (unsigned int)f2bf(p[0]) | ((unsigned int)f2bf(p[1]) << 16);
        w.y = (unsigned int)f2bf(p[2]) | ((unsigned int)f2bf(p[3]) << 16);
        *(uint2*)(Pb + l15 * 40 + n2 * 16 + lhi * 4) = w;
    }
    // single-wave block: LDS write->read ordering needs only lgkmcnt drain (no barrier,
    // keeps outstanding global V/K loads (vmcnt) in flight)
    asm volatile("s_waitcnt lgkmcnt(0)" ::: "memory");
    bf16x8 pf = *(const bf16x8*)(Pb + l15 * 40 + lhi * 8);
#pragma unroll
    for (int dt = 0; dt < 8; ++dt)
        o[dt] = MFMA16(pf, vf[dt], o[dt]);
}

__global__ __launch_bounds__(64) void attn_k(const ushort* __restrict__ q1b, const ushort* __restrict__ q2b,
                                             const ushort* __restrict__ kb, const ushort* __restrict__ vtb,
                                             ushort* __restrict__ aob) {
    const int h = blockIdx.x & 15;
    const int strip = 127 - (int)(blockIdx.x >> 4);  // global longest-first ordering
    const int q0 = strip << 4;
    const int lane = threadIdx.x;
    const int l15 = lane & 15;
    const int lhi = lane >> 4;
    const int qrow = q0 + l15;

    bf16x8 q1f[4], q2f[4];
    {
        size_t base = (size_t)qrow * 2048 + h * 128 + lhi * 8;
#pragma unroll
        for (int c = 0; c < 4; ++c) {
            q1f[c] = *(const bf16x8*)(q1b + base + c * 32);
            q2f[c] = *(const bf16x8*)(q2b + base + c * 32);
        }
    }

    const int nchunk = (strip >> 1) + 1;
    const int nfull = nchunk - 1;

    // ---- pass 1: row sums of exp(s) (lane-local, no shuffles in loop) ----
    float sum1 = 0.f, sum2 = 0.f;
    for (int ch = 0; ch < nfull; ++ch)
        pass1_chunk<false>(ch << 5, l15, lhi, qrow, q1f, q2f, kb, sum1, sum2);
    pass1_chunk<true>(nfull << 5, l15, lhi, qrow, q1f, q2f, kb, sum1, sum2);

    // combine the 4 lane-groups (each lane ends with the full row sum for row l15)
    sum1 += __shfl_xor(sum1, 16);
    sum1 += __shfl_xor(sum1, 32);
    sum2 += __shfl_xor(sum2, 16);
    sum2 += __shfl_xor(sum2, 32);

    // a = (a1 - 0.5*a2) / (0.5 + 1e-8); a1 = exp(s1)/sum1
    const float inv_denom = 1.0f / (0.5f + 1e-8f);
    const float c1 = inv_denom / sum1;
    const float c2 = 0.5f * inv_denom / sum2;

    __shared__ ushort P[2][16][40];
    f32x4 o[8];
#pragma unroll
    for (int dt = 0; dt < 8; ++dt) o[dt] = (f32x4){0.f, 0.f, 0.f, 0.f};

    // ---- pass 2: probabilities + PV (double-buffered P) ----
    for (int ch = 0; ch < nfull; ++ch)
        pass2_chunk<false>(ch << 5, &P[ch & 1][0][0], l15, lhi, qrow, q1f, q2f, kb, vtb, c1, c2, o);
    pass2_chunk<true>(nfull << 5, &P[nfull & 1][0][0], l15, lhi, qrow, q1f, q2f, kb, vtb, c1, c2, o);

#pragma unroll
    for (int dt = 0; dt < 8; ++dt)
#pragma unroll
        for (int r = 0; r < 4; ++r)
            aob[(size_t)(q0 + lhi * 4 + r) * 2048 + h * 128 + dt * 16 + l15] = f2bf(o[dt][r]);
}

extern "C" void kernel_launch(void* const* d_in, const int* in_sizes, int n_in,
                              void* d_out, int out_size, void* d_ws, size_t ws_size,
                              hipStream_t stream) {
    const int S = 2048, HID = 2048, QD = 2048, HD = 128;

    const float* x = (const float*)d_in[0];
    const float* fcos = (const float*)d_in[1];
    const float* fsin = (const float*)d_in[2];
    // d_in[3] = mask (causal, implicit)
    const float* q1w = (const float*)d_in[4];
    const float* q2w = (const float*)d_in[5];
    const float* kw = (const float*)d_in[6];
    const float* vw = (const float*)d_in[7];
    const float* ow = (const float*)d_in[8];

    char* w = (char*)d_ws;
    ushort* xb = (ushort*)w;   w += (size_t)S * HID * 2;       // 8 MB
    ushort* w1t = (ushort*)w;  w += (size_t)QD * HID * 2;      // 8 MB
    ushort* w2t = (ushort*)w;  w += (size_t)QD * HID * 2;      // 8 MB
    ushort* wot = (ushort*)w;  w += (size_t)HID * QD * 2;      // 8 MB
    ushort* wkt = (ushort*)w;  w += (size_t)HD * HID * 2;      // 0.5 MB
    ushort* wvt = (ushort*)w;  w += (size_t)HD * HID * 2;      // 0.5 MB
    ushort* q1b = (ushort*)w;  w += (size_t)S * QD * 2;        // 8 MB
    ushort* q2b = (ushort*)w;  w += (size_t)S * QD * 2;        // 8 MB
    ushort* kbx = (ushort*)w;  w += (size_t)S * HD * 2;        // 0.5 MB
    ushort* vb = (ushort*)w;   w += (size_t)S * HD * 2;        // 0.5 MB
    ushort* vtb = (ushort*)w;  w += (size_t)HD * S * 2;        // 0.5 MB
    ushort* aob = (ushort*)w;  w += (size_t)S * QD * 2;        // 8 MB

    // 1. convert x -> bf16
    cvt_f32_bf16_k<<<dim3((S * HID / 4 + 255) / 256), dim3(256), 0, stream>>>(x, xb, S * HID / 4);

    // 2. transpose+convert weights -> [N][K] bf16
    tpc_f32_bf16_k<<<dim3(QD / 32, HID / 32), dim3(256), 0, stream>>>(q1w, w1t, HID, QD);
    tpc_f32_bf16_k<<<dim3(QD / 32, HID / 32), dim3(256), 0, stream>>>(q2w, w2t, HID, QD);
    tpc_f32_bf16_k<<<dim3(HD / 32, HID / 32), dim3(256), 0, stream>>>(kw, wkt, HID, HD);
    tpc_f32_bf16_k<<<dim3(HD / 32, HID / 32), dim3(256), 0, stream>>>(vw, wvt, HID, HD);
    tpc_f32_bf16_k<<<dim3(HID / 32, QD / 32), dim3(256), 0, stream>>>(ow, wot, QD, HID);

    // 3. projections (bf16 out)
    gemm_bf16_k<<<dim3(S / 128, QD / 128), dim3(256), 0, stream>>>(xb, w1t, q1b, S, QD, HID, 1);
    gemm_bf16_k<<<dim3(S / 128, QD / 128), dim3(256), 0, stream>>>(xb, w2t, q2b, S, QD, HID, 1);
    gemm_bf16_k<<<dim3(S / 128, HD / 128), dim3(256), 0, stream>>>(xb, wkt, kbx, S, HD, HID, 1);
    gemm_bf16_k<<<dim3(S / 128, HD / 128), dim3(256), 0, stream>>>(xb, wvt, vb, S, HD, HID, 1);

    // 4. RoPE in-place (q1, q2: 16 heads; k: 1 head)
    rope_k<<<dim3(S * 16 * 64 / 256), dim3(256), 0, stream>>>(q1b, fcos, fsin, 16);
    rope_k<<<dim3(S * 16 * 64 / 256), dim3(256), 0, stream>>>(q2b, fcos, fsin, 16);
    rope_k<<<dim3(S * 1 * 64 / 256), dim3(256), 0, stream>>>(kbx, fcos, fsin, 1);

    // 5. V -> Vt [128][2048]
    tp_bf16_k<<<dim3(HD / 32, S / 32), dim3(256), 0, stream>>>(vb, vtb, S, HD);

    // 6. attention
    attn_k<<<dim3(16 * 128), dim3(64), 0, stream>>>(q1b, q2b, kbx, vtb, aob);

    // 7. output projection (f32 out to d_out)
    gemm_bf16_k<<<dim3(S / 128, HID / 128), dim3(256), 0, stream>>>(aob, wot, (float*)d_out, S, HID, QD, 0);
}

// Round 3
// 359.826 us; speedup vs baseline: 2.1519x; 1.4180x over previous
//
#include <hip/hip_runtime.h>
#include <hip/hip_bf16.h>

typedef __attribute__((ext_vector_type(8))) short bf16x8;
typedef __attribute__((ext_vector_type(4))) float f32x4;

#define MFMA16(a, b, c) __builtin_amdgcn_mfma_f32_16x16x32_bf16((a), (b), (c), 0, 0, 0)

#define ATTN_SCALE 0.08838834764831845f  // 1/sqrt(128)
#define LDQ 4352                          // fused qkv row stride (2048+2048+128+128)

__device__ __forceinline__ ushort f2bf(float f) {
    unsigned int x = __float_as_uint(f);
    x += 0x7fffu + ((x >> 16) & 1u);
    return (ushort)(x >> 16);
}
__device__ __forceinline__ float bf2f(ushort u) {
    return __uint_as_float(((unsigned int)u) << 16);
}

__device__ __forceinline__ void gload16(const ushort* g, ushort* l) {
    __builtin_amdgcn_global_load_lds((const __attribute__((address_space(1))) unsigned int*)g,
                                     (__attribute__((address_space(3))) unsigned int*)l, 16, 0, 0);
}

// ---------------- f32 -> bf16 flat convert ----------------
__global__ void cvt_f32_bf16_k(const float* __restrict__ in, ushort* __restrict__ out, int n4) {
    int i = blockIdx.x * blockDim.x + threadIdx.x;
    if (i >= n4) return;
    float4 v = ((const float4*)in)[i];
    ushort4 u;
    u.x = f2bf(v.x); u.y = f2bf(v.y); u.z = f2bf(v.z); u.w = f2bf(v.w);
    ((ushort4*)out)[i] = u;
}

// ---------------- transpose + convert: in f32 [R][C] -> out bf16 [C][R] ----------------
__global__ __launch_bounds__(256) void tpc_f32_bf16_k(const float* __restrict__ in, ushort* __restrict__ out,
                                                      int R, int C) {
    __shared__ ushort t[32][33];
    const int c0 = blockIdx.x * 32, r0 = blockIdx.y * 32;
    const int lx = threadIdx.x & 31, ly = threadIdx.x >> 5;
#pragma unroll
    for (int i = 0; i < 4; ++i)
        t[ly + i * 8][lx] = f2bf(in[(size_t)(r0 + ly + i * 8) * C + c0 + lx]);
    __syncthreads();
#pragma unroll
    for (int i = 0; i < 4; ++i)
        out[(size_t)(c0 + ly + i * 8) * R + r0 + lx] = t[lx][ly + i * 8];
}

// ---------------- strided transpose bf16: in [R][C] (row stride ldin) -> out [C][R] ----------------
__global__ __launch_bounds__(256) void tp_bf16_k(const ushort* __restrict__ in, int ldin,
                                                 ushort* __restrict__ out, int R, int C) {
    __shared__ ushort t[32][33];
    const int c0 = blockIdx.x * 32, r0 = blockIdx.y * 32;
    const int lx = threadIdx.x & 31, ly = threadIdx.x >> 5;
#pragma unroll
    for (int i = 0; i < 4; ++i)
        t[ly + i * 8][lx] = in[(size_t)(r0 + ly + i * 8) * ldin + c0 + lx];
    __syncthreads();
#pragma unroll
    for (int i = 0; i < 4; ++i)
        out[(size_t)(c0 + ly + i * 8) * R + r0 + lx] = t[lx][ly + i * 8];
}

// ---------------- fused RoPE over q1|q2|k columns of qkv [S][LDQ] (33 head-slots) ----------------
__global__ void rope_k(ushort* __restrict__ t, const float* __restrict__ cs, const float* __restrict__ sn) {
    int i = blockIdx.x * blockDim.x + threadIdx.x;  // over S*33*64
    int d = i & 63;
    int rest = i >> 6;
    int s = rest / 33;
    int h = rest - s * 33;
    size_t base = (size_t)s * LDQ + h * 128;
    float t0 = bf2f(t[base + d]);
    float t1 = bf2f(t[base + d + 64]);
    float cA = cs[s * 128 + d], cB = cs[s * 128 + d + 64];
    float sA = sn[s * 128 + d], sB = sn[s * 128 + d + 64];
    t[base + d] = f2bf(t0 * cA - t1 * sA);
    t[base + d + 64] = f2bf(t1 * cB + t0 * sB);
}

// ---------------- bf16 GEMM (m97-style global_load_lds staging) ----------------
// C[M][ldc] = A[M][lda] @ Bt[N][ldb]^T. 128x128 tile, BK=32, 4 waves (2x2).
__global__ __launch_bounds__(256) void gemm_glds_k(const ushort* __restrict__ A, int lda,
                                                   const ushort* __restrict__ Bt, int ldb,
                                                   void* __restrict__ C, int ldc,
                                                   int M, int N, int K, int cbf) {
    __shared__ ushort As[128 * 32];
    __shared__ ushort Bs[128 * 32];
    const int tid = threadIdx.x;
    const int m0 = blockIdx.x * 128, n0 = blockIdx.y * 128;
    const int lane = tid & 63, wid = tid >> 6;
    const int wr = wid >> 1, wc = wid & 1;
    const int l15 = lane & 15, lhi = lane >> 4;

    // staging geometry: 8 segments of 16 rows (1KB); wave w stages segs {2w, 2w+1} of A and B.
    // lane l covers row (l>>2) of the segment, 16B at k-offset (l&3)*8 elements.
    const int srow = lane >> 2, skq = (lane & 3) * 8;
    const ushort* gA0 = A + (size_t)(m0 + (wid * 2 + 0) * 16 + srow) * lda + skq;
    const ushort* gA1 = A + (size_t)(m0 + (wid * 2 + 1) * 16 + srow) * lda + skq;
    const ushort* gB0 = Bt + (size_t)(n0 + (wid * 2 + 0) * 16 + srow) * ldb + skq;
    const ushort* gB1 = Bt + (size_t)(n0 + (wid * 2 + 1) * 16 + srow) * ldb + skq;
    ushort* lA0 = &As[(wid * 2 + 0) * 512];
    ushort* lA1 = &As[(wid * 2 + 1) * 512];
    ushort* lB0 = &Bs[(wid * 2 + 0) * 512];
    ushort* lB1 = &Bs[(wid * 2 + 1) * 512];

    f32x4 acc[4][4];
#pragma unroll
    for (int m = 0; m < 4; ++m)
#pragma unroll
        for (int n = 0; n < 4; ++n) acc[m][n] = (f32x4){0.f, 0.f, 0.f, 0.f};

    for (int k0 = 0; k0 < K; k0 += 32) {
        __syncthreads();  // previous iter's ds_reads done before overwrite
        gload16(gA0 + k0, lA0);
        gload16(gA1 + k0, lA1);
        gload16(gB0 + k0, lB0);
        gload16(gB1 + k0, lB1);
        __syncthreads();  // compiler drains vmcnt(0) before s_barrier -> staging complete
        bf16x8 af[4], bfr[4];
#pragma unroll
        for (int m = 0; m < 4; ++m)
            af[m] = *(const bf16x8*)&As[(wr * 64 + m * 16 + l15) * 32 + lhi * 8];
#pragma unroll
        for (int n = 0; n < 4; ++n)
            bfr[n] = *(const bf16x8*)&Bs[(wc * 64 + n * 16 + l15) * 32 + lhi * 8];
#pragma unroll
        for (int m = 0; m < 4; ++m)
#pragma unroll
            for (int n = 0; n < 4; ++n)
                acc[m][n] = MFMA16(af[m], bfr[n], acc[m][n]);
    }

#pragma unroll
    for (int m = 0; m < 4; ++m) {
        const int rb = m0 + wr * 64 + m * 16 + lhi * 4;
#pragma unroll
        for (int n = 0; n < 4; ++n) {
            const int col = n0 + wc * 64 + n * 16 + l15;
#pragma unroll
            for (int r = 0; r < 4; ++r) {
                if (cbf)
                    ((ushort*)C)[(size_t)(rb + r) * ldc + col] = f2bf(acc[m][n][r]);
                else
                    ((float*)C)[(size_t)(rb + r) * ldc + col] = acc[m][n][r];
            }
        }
    }
}

// ---------------- differential MQA attention, column-split 2x ----------------
// qkv rows: [0:2048)=q1, [2048:4096)=q2, [4096:4224)=k, [4224:4352)=v (all bf16, stride LDQ).

template <bool MASKED>
__device__ __forceinline__ void pass1_chunk(int kc, int l15, int lhi, int qrow,
                                            const bf16x8* q1f, const bf16x8* q2f,
                                            const ushort* __restrict__ kb,
                                            float& sum1, float& sum2) {
    bf16x8 kf[2][4];
#pragma unroll
    for (int n2 = 0; n2 < 2; ++n2)
#pragma unroll
        for (int c = 0; c < 4; ++c)
            kf[n2][c] = *(const bf16x8*)(kb + (size_t)(kc + n2 * 16 + l15) * LDQ + lhi * 8 + c * 32);
    f32x4 s1[2], s2[2];
#pragma unroll
    for (int n2 = 0; n2 < 2; ++n2) {
        s1[n2] = (f32x4){0.f, 0.f, 0.f, 0.f};
        s2[n2] = (f32x4){0.f, 0.f, 0.f, 0.f};
#pragma unroll
        for (int c = 0; c < 4; ++c) {
            s1[n2] = MFMA16(kf[n2][c], q1f[c], s1[n2]);
            s2[n2] = MFMA16(kf[n2][c], q2f[c], s2[n2]);
        }
    }
    const int kbase = kc + lhi * 4;
#pragma unroll
    for (int n2 = 0; n2 < 2; ++n2)
#pragma unroll
        for (int r = 0; r < 4; ++r) {
            float e1 = __expf(s1[n2][r] * ATTN_SCALE);
            float e2 = __expf(s2[n2][r] * ATTN_SCALE);
            if (MASKED) {
                bool ok = (kbase + n2 * 16 + r) <= qrow;
                e1 = ok ? e1 : 0.f;
                e2 = ok ? e2 : 0.f;
            }
            sum1 += e1;
            sum2 += e2;
        }
}

__global__ __launch_bounds__(64, 4) void attn_sums_k(const ushort* __restrict__ qkv,
                                                     float* __restrict__ sums) {
    const int h = blockIdx.x & 15;
    const int cs = (blockIdx.x >> 4) & 1;
    const int strip = 127 - (int)(blockIdx.x >> 5);  // longest-first
    const int q0 = strip << 4;
    const int lane = threadIdx.x;
    const int l15 = lane & 15, lhi = lane >> 4;
    const int qrow = q0 + l15;

    bf16x8 q1f[4], q2f[4];
    {
        size_t base = (size_t)qrow * LDQ + h * 128 + lhi * 8;
#pragma unroll
        for (int c = 0; c < 4; ++c) {
            q1f[c] = *(const bf16x8*)(qkv + base + c * 32);
            q2f[c] = *(const bf16x8*)(qkv + base + 2048 + c * 32);
        }
    }
    const ushort* kb = qkv + 4096;

    const int nchunk = (strip >> 1) + 1;
    const int ndiag = nchunk - 1;

    float sum1 = 0.f, sum2 = 0.f;
    for (int ch = cs; ch < ndiag; ch += 2)
        pass1_chunk<false>(ch << 5, l15, lhi, qrow, q1f, q2f, kb, sum1, sum2);
    if ((ndiag & 1) == cs)
        pass1_chunk<true>(ndiag << 5, l15, lhi, qrow, q1f, q2f, kb, sum1, sum2);

    sum1 += __shfl_xor(sum1, 16);
    sum1 += __shfl_xor(sum1, 32);
    sum2 += __shfl_xor(sum2, 16);
    sum2 += __shfl_xor(sum2, 32);

    if (lhi == 0) {
        sums[(size_t)((cs * 2 + 0) * 16 + h) * 2048 + qrow] = sum1;
        sums[(size_t)((cs * 2 + 1) * 16 + h) * 2048 + qrow] = sum2;
    }
}

template <bool MASKED>
__device__ __forceinline__ void pass2_chunk(int kc, ushort* __restrict__ Pb,
                                            int l15, int lhi, int qrow,
                                            const bf16x8* q1f, const bf16x8* q2f,
                                            const ushort* __restrict__ kb,
                                            const ushort* __restrict__ vtb,
                                            float c1, float c2, f32x4* o) {
    bf16x8 vf[8];
#pragma unroll
    for (int dt = 0; dt < 8; ++dt)
        vf[dt] = *(const bf16x8*)(vtb + (size_t)(dt * 16 + l15) * 2048 + kc + lhi * 8);
    bf16x8 kf[2][4];
#pragma unroll
    for (int n2 = 0; n2 < 2; ++n2)
#pragma unroll
        for (int c = 0; c < 4; ++c)
            kf[n2][c] = *(const bf16x8*)(kb + (size_t)(kc + n2 * 16 + l15) * LDQ + lhi * 8 + c * 32);
    f32x4 s1[2], s2[2];
#pragma unroll
    for (int n2 = 0; n2 < 2; ++n2) {
        s1[n2] = (f32x4){0.f, 0.f, 0.f, 0.f};
        s2[n2] = (f32x4){0.f, 0.f, 0.f, 0.f};
#pragma unroll
        for (int c = 0; c < 4; ++c) {
            s1[n2] = MFMA16(kf[n2][c], q1f[c], s1[n2]);
            s2[n2] = MFMA16(kf[n2][c], q2f[c], s2[n2]);
        }
    }
    const int kbase = kc + lhi * 4;
#pragma unroll
    for (int n2 = 0; n2 < 2; ++n2) {
        float p[4];
#pragma unroll
        for (int r = 0; r < 4; ++r) {
            float e1 = __expf(s1[n2][r] * ATTN_SCALE) * c1;
            float e2 = __expf(s2[n2][r] * ATTN_SCALE) * c2;
            float pv = fmaxf(e1 - e2, 0.f);
            if (MASKED) pv = ((kbase + n2 * 16 + r) <= qrow) ? pv : 0.f;
            p[r] = pv;
        }
        uint2 w;
        w.x = (unsigned int)f2bf(p[0]) | ((unsigned int)f2bf(p[1]) << 16);
        w.y = (unsigned int)f2bf(p[2]) | ((unsigned int)f2bf(p[3]) << 16);
        *(uint2*)(Pb + l15 * 40 + n2 * 16 + lhi * 4) = w;
    }
    // single-wave block: LDS write->read needs only lgkmcnt drain (keeps vmcnt loads in flight)
    asm volatile("s_waitcnt lgkmcnt(0)" ::: "memory");
    bf16x8 pf = *(const bf16x8*)(Pb + l15 * 40 + lhi * 8);
#pragma unroll
    for (int dt = 0; dt < 8; ++dt)
        o[dt] = MFMA16(pf, vf[dt], o[dt]);
}

__global__ __launch_bounds__(64, 4) void attn_pv_k(const ushort* __restrict__ qkv,
                                                   const ushort* __restrict__ vtb,
                                                   const float* __restrict__ sums,
                                                   ushort* __restrict__ op0,
                                                   ushort* __restrict__ op1) {
    const int h = blockIdx.x & 15;
    const int cs = (blockIdx.x >> 4) & 1;
    const int strip = 127 - (int)(blockIdx.x >> 5);
    const int q0 = strip << 4;
    const int lane = threadIdx.x;
    const int l15 = lane & 15, lhi = lane >> 4;
    const int qrow = q0 + l15;

    bf16x8 q1f[4], q2f[4];
    {
        size_t base = (size_t)qrow * LDQ + h * 128 + lhi * 8;
#pragma unroll
        for (int c = 0; c < 4; ++c) {
            q1f[c] = *(const bf16x8*)(qkv + base + c * 32);
            q2f[c] = *(const bf16x8*)(qkv + base + 2048 + c * 32);
        }
    }
    const ushort* kb = qkv + 4096;

    const float sum1 = sums[(size_t)(0 * 16 + h) * 2048 + qrow] + sums[(size_t)(2 * 16 + h) * 2048 + qrow];
    const float sum2 = sums[(size_t)(1 * 16 + h) * 2048 + qrow] + sums[(size_t)(3 * 16 + h) * 2048 + qrow];
    const float inv_denom = 1.0f / (0.5f + 1e-8f);
    const float c1 = inv_denom / sum1;
    const float c2 = 0.5f * inv_denom / sum2;

    __shared__ ushort P[2][16][40];
    f32x4 o[8];
#pragma unroll
    for (int dt = 0; dt < 8; ++dt) o[dt] = (f32x4){0.f, 0.f, 0.f, 0.f};

    const int nchunk = (strip >> 1) + 1;
    const int ndiag = nchunk - 1;
    int pb = 0;
    for (int ch = cs; ch < ndiag; ch += 2, pb ^= 1)
        pass2_chunk<false>(ch << 5, &P[pb][0][0], l15, lhi, qrow, q1f, q2f, kb, vtb, c1, c2, o);
    if ((ndiag & 1) == cs)
        pass2_chunk<true>(ndiag << 5, &P[pb][0][0], l15, lhi, qrow, q1f, q2f, kb, vtb, c1, c2, o);

    ushort* op = cs ? op1 : op0;
#pragma unroll
    for (int dt = 0; dt < 8; ++dt)
#pragma unroll
        for (int r = 0; r < 4; ++r)
            op[(size_t)(q0 + lhi * 4 + r) * 2048 + h * 128 + dt * 16 + l15] = f2bf(o[dt][r]);
}

// ---------------- combine partial O halves: aob = bf16(op0 + op1) ----------------
__device__ __forceinline__ unsigned int addbf2(unsigned int a, unsigned int b) {
    float alo = bf2f((ushort)a), ahi = bf2f((ushort)(a >> 16));
    float blo = bf2f((ushort)b), bhi = bf2f((ushort)(b >> 16));
    return (unsigned int)f2bf(alo + blo) | ((unsigned int)f2bf(ahi + bhi) << 16);
}
__global__ void combine_k(const ushort* __restrict__ o0, const ushort* __restrict__ o1,
                          ushort* __restrict__ out, int n8) {
    int i = blockIdx.x * blockDim.x + threadIdx.x;
    if (i >= n8) return;
    uint4 a = ((const uint4*)o0)[i];
    uint4 b = ((const uint4*)o1)[i];
    uint4 c;
    c.x = addbf2(a.x, b.x);
    c.y = addbf2(a.y, b.y);
    c.z = addbf2(a.z, b.z);
    c.w = addbf2(a.w, b.w);
    ((uint4*)out)[i] = c;
}

extern "C" void kernel_launch(void* const* d_in, const int* in_sizes, int n_in,
                              void* d_out, int out_size, void* d_ws, size_t ws_size,
                              hipStream_t stream) {
    const int S = 2048, HID = 2048;

    const float* x = (const float*)d_in[0];
    const float* fcos = (const float*)d_in[1];
    const float* fsin = (const float*)d_in[2];
    // d_in[3] = mask (causal, implicit)
    const float* q1w = (const float*)d_in[4];
    const float* q2w = (const float*)d_in[5];
    const float* kw = (const float*)d_in[6];
    const float* vw = (const float*)d_in[7];
    const float* ow = (const float*)d_in[8];

    // workspace layout (shorts); ws proven >= 58.5MB by round-1 layout
    ushort* xb = (ushort*)d_ws;                        // 4M shorts (8MB); dead after QKV GEMM -> opart0
    ushort* btq = xb + (size_t)4194304;                // fused Bt: w1t|w2t|wkt|wvt = 8912896 shorts (17MB)
    ushort* w1t = btq;                                 //   rows [0,2048)    ; dead after GEMM -> opart1
    ushort* w2t = btq + (size_t)2048 * 2048;           //   rows [2048,4096) ; dead after GEMM -> aob
    ushort* wkt = btq + (size_t)4096 * 2048;           //   rows [4096,4224)
    ushort* wvt = btq + (size_t)4224 * 2048;           //   rows [4224,4352)
    ushort* wot = btq + (size_t)8912896;               // 4M shorts (8MB)
    ushort* qkvb = wot + (size_t)4194304;              // 2048*4352 shorts (17MB)
    ushort* vtb = qkvb + (size_t)8912896;              // 128*2048 shorts (0.5MB)
    float* sums = (float*)(vtb + (size_t)262144);      // 4*16*2048 f32 (0.5MB)
    ushort* opart0 = xb;                               // reuse
    ushort* opart1 = w1t;                              // reuse
    ushort* aob = w2t;                                 // reuse

    // 1. convert x -> bf16
    cvt_f32_bf16_k<<<dim3(4096), dim3(256), 0, stream>>>(x, xb, S * HID / 4);

    // 2. transpose+convert weights into fused Bt and wot
    tpc_f32_bf16_k<<<dim3(64, 64), dim3(256), 0, stream>>>(q1w, w1t, HID, 2048);
    tpc_f32_bf16_k<<<dim3(64, 64), dim3(256), 0, stream>>>(q2w, w2t, HID, 2048);
    tpc_f32_bf16_k<<<dim3(4, 64), dim3(256), 0, stream>>>(kw, wkt, HID, 128);
    tpc_f32_bf16_k<<<dim3(4, 64), dim3(256), 0, stream>>>(vw, wvt, HID, 128);
    tpc_f32_bf16_k<<<dim3(64, 64), dim3(256), 0, stream>>>(ow, wot, 2048, HID);

    // 3. fused QKV projection: qkvb[2048][4352] = xb @ btq^T
    gemm_glds_k<<<dim3(16, 34), dim3(256), 0, stream>>>(xb, HID, btq, HID, qkvb, LDQ, S, LDQ, HID, 1);

    // 4. fused RoPE over q1|q2|k head-slots (33 slots x 64 pairs)
    rope_k<<<dim3(16896), dim3(256), 0, stream>>>(qkvb, fcos, fsin);

    // 5. V -> Vt [128][2048]
    tp_bf16_k<<<dim3(4, 64), dim3(256), 0, stream>>>(qkvb + 4224, LDQ, vtb, S, 128);

    // 6. attention pass 1 (exp-sums), column-split 2x
    attn_sums_k<<<dim3(4096), dim3(64), 0, stream>>>(qkvb, sums);

    // 7. attention pass 2 (PV partials), column-split 2x
    attn_pv_k<<<dim3(4096), dim3(64), 0, stream>>>(qkvb, vtb, sums, opart0, opart1);

    // 8. combine halves -> aob
    combine_k<<<dim3(2048), dim3(256), 0, stream>>>(opart0, opart1, aob, S * HID / 8);

    // 9. output projection (f32 out)
    gemm_glds_k<<<dim3(16, 16), dim3(256), 0, stream>>>(aob, HID, wot, HID, (float*)d_out, HID, S, HID, HID, 0);
}

// Round 4
// 240.097 us; speedup vs baseline: 3.2250x; 1.4987x over previous
//
#include <hip/hip_runtime.h>
#include <hip/hip_bf16.h>

typedef __attribute__((ext_vector_type(8))) short bf16x8;
typedef __attribute__((ext_vector_type(4))) float f32x4;

#define MFMA16(a, b, c) __builtin_amdgcn_mfma_f32_16x16x32_bf16((a), (b), (c), 0, 0, 0)

#define ATTN_SCALE 0.08838834764831845f  // 1/sqrt(128)
#define LDQ 4352                          // fused qkv row stride (2048+2048+128+128)

__device__ __forceinline__ ushort f2bf(float f) {
    unsigned int x = __float_as_uint(f);
    x += 0x7fffu + ((x >> 16) & 1u);
    return (ushort)(x >> 16);
}
__device__ __forceinline__ float bf2f(ushort u) {
    return __uint_as_float(((unsigned int)u) << 16);
}

__device__ __forceinline__ void gload16(const ushort* g, ushort* l) {
    __builtin_amdgcn_global_load_lds((const __attribute__((address_space(1))) unsigned int*)g,
                                     (__attribute__((address_space(3))) unsigned int*)l, 16, 0, 0);
}

// ---------------- f32 -> bf16 flat convert ----------------
__global__ void cvt_f32_bf16_k(const float* __restrict__ in, ushort* __restrict__ out, int n4) {
    int i = blockIdx.x * blockDim.x + threadIdx.x;
    if (i >= n4) return;
    float4 v = ((const float4*)in)[i];
    ushort4 u;
    u.x = f2bf(v.x); u.y = f2bf(v.y); u.z = f2bf(v.z); u.w = f2bf(v.w);
    ((ushort4*)out)[i] = u;
}

// ---------------- transpose + convert: in f32 [R][C] -> out bf16 [C][R] ----------------
__global__ __launch_bounds__(256) void tpc_f32_bf16_k(const float* __restrict__ in, ushort* __restrict__ out,
                                                      int R, int C) {
    __shared__ ushort t[32][33];
    const int c0 = blockIdx.x * 32, r0 = blockIdx.y * 32;
    const int lx = threadIdx.x & 31, ly = threadIdx.x >> 5;
#pragma unroll
    for (int i = 0; i < 4; ++i)
        t[ly + i * 8][lx] = f2bf(in[(size_t)(r0 + ly + i * 8) * C + c0 + lx]);
    __syncthreads();
#pragma unroll
    for (int i = 0; i < 4; ++i)
        out[(size_t)(c0 + ly + i * 8) * R + r0 + lx] = t[lx][ly + i * 8];
}

// ---------------- strided transpose bf16: in [R][C] (row stride ldin) -> out [C][R] ----------------
__global__ __launch_bounds__(256) void tp_bf16_k(const ushort* __restrict__ in, int ldin,
                                                 ushort* __restrict__ out, int R, int C) {
    __shared__ ushort t[32][33];
    const int c0 = blockIdx.x * 32, r0 = blockIdx.y * 32;
    const int lx = threadIdx.x & 31, ly = threadIdx.x >> 5;
#pragma unroll
    for (int i = 0; i < 4; ++i)
        t[ly + i * 8][lx] = in[(size_t)(r0 + ly + i * 8) * ldin + c0 + lx];
    __syncthreads();
#pragma unroll
    for (int i = 0; i < 4; ++i)
        out[(size_t)(c0 + ly + i * 8) * R + r0 + lx] = t[lx][ly + i * 8];
}

// ---------------- fused RoPE over q1|q2|k columns of qkv [S][LDQ] (33 head-slots) ----------------
__global__ void rope_k(ushort* __restrict__ t, const float* __restrict__ cs, const float* __restrict__ sn) {
    int i = blockIdx.x * blockDim.x + threadIdx.x;  // over S*33*64
    int d = i & 63;
    int rest = i >> 6;
    int s = rest / 33;
    int h = rest - s * 33;
    size_t base = (size_t)s * LDQ + h * 128;
    float t0 = bf2f(t[base + d]);
    float t1 = bf2f(t[base + d + 64]);
    float cA = cs[s * 128 + d], cB = cs[s * 128 + d + 64];
    float sA = sn[s * 128 + d], sB = sn[s * 128 + d + 64];
    t[base + d] = f2bf(t0 * cA - t1 * sA);
    t[base + d + 64] = f2bf(t1 * cB + t0 * sB);
}

// ---------------- bf16 GEMM (m97-style global_load_lds staging) ----------------
__global__ __launch_bounds__(256) void gemm_glds_k(const ushort* __restrict__ A, int lda,
                                                   const ushort* __restrict__ Bt, int ldb,
                                                   void* __restrict__ C, int ldc,
                                                   int M, int N, int K, int cbf) {
    __shared__ ushort As[128 * 32];
    __shared__ ushort Bs[128 * 32];
    const int tid = threadIdx.x;
    const int m0 = blockIdx.x * 128, n0 = blockIdx.y * 128;
    const int lane = tid & 63, wid = tid >> 6;
    const int wr = wid >> 1, wc = wid & 1;
    const int l15 = lane & 15, lhi = lane >> 4;

    const int srow = lane >> 2, skq = (lane & 3) * 8;
    const ushort* gA0 = A + (size_t)(m0 + (wid * 2 + 0) * 16 + srow) * lda + skq;
    const ushort* gA1 = A + (size_t)(m0 + (wid * 2 + 1) * 16 + srow) * lda + skq;
    const ushort* gB0 = Bt + (size_t)(n0 + (wid * 2 + 0) * 16 + srow) * ldb + skq;
    const ushort* gB1 = Bt + (size_t)(n0 + (wid * 2 + 1) * 16 + srow) * ldb + skq;
    ushort* lA0 = &As[(wid * 2 + 0) * 512];
    ushort* lA1 = &As[(wid * 2 + 1) * 512];
    ushort* lB0 = &Bs[(wid * 2 + 0) * 512];
    ushort* lB1 = &Bs[(wid * 2 + 1) * 512];

    f32x4 acc[4][4];
#pragma unroll
    for (int m = 0; m < 4; ++m)
#pragma unroll
        for (int n = 0; n < 4; ++n) acc[m][n] = (f32x4){0.f, 0.f, 0.f, 0.f};

    for (int k0 = 0; k0 < K; k0 += 32) {
        __syncthreads();
        gload16(gA0 + k0, lA0);
        gload16(gA1 + k0, lA1);
        gload16(gB0 + k0, lB0);
        gload16(gB1 + k0, lB1);
        __syncthreads();
        bf16x8 af[4], bfr[4];
#pragma unroll
        for (int m = 0; m < 4; ++m)
            af[m] = *(const bf16x8*)&As[(wr * 64 + m * 16 + l15) * 32 + lhi * 8];
#pragma unroll
        for (int n = 0; n < 4; ++n)
            bfr[n] = *(const bf16x8*)&Bs[(wc * 64 + n * 16 + l15) * 32 + lhi * 8];
#pragma unroll
        for (int m = 0; m < 4; ++m)
#pragma unroll
            for (int n = 0; n < 4; ++n)
                acc[m][n] = MFMA16(af[m], bfr[n], acc[m][n]);
    }

#pragma unroll
    for (int m = 0; m < 4; ++m) {
        const int rb = m0 + wr * 64 + m * 16 + lhi * 4;
#pragma unroll
        for (int n = 0; n < 4; ++n) {
            const int col = n0 + wc * 64 + n * 16 + l15;
#pragma unroll
            for (int r = 0; r < 4; ++r) {
                if (cbf)
                    ((ushort*)C)[(size_t)(rb + r) * ldc + col] = f2bf(acc[m][n][r]);
                else
                    ((float*)C)[(size_t)(rb + r) * ldc + col] = acc[m][n][r];
            }
        }
    }
}

// ---------------- differential MQA attention ----------------
// Blocks of 4 waves = 4 heads sharing one 16-row q-strip; K (and V) chunks staged
// once per block into double-buffered, XOR-swizzled LDS (global_load_lds, linear
// dest + pre-swizzled global source + swizzled read — rule #21).
// K tile [32][128] bf16 (256B rows): byte ^= (row&7)<<4.
// V tile [128][32] bf16 (64B rows):  byte ^= ((row>>1)&3)<<4.

__device__ __forceinline__ void stage_k_chunk(const ushort* __restrict__ kb, int kc,
                                              ushort* __restrict__ kbuf, int wid, int lane) {
#pragma unroll
    for (int u = 0; u < 2; ++u) {
        const int w = wid * 2 + u;
        const int row = w * 4 + (lane >> 4);
        const int colb = ((lane & 15) * 16) ^ ((row & 7) << 4);
        gload16(kb + (size_t)(kc + row) * LDQ + (colb >> 1), kbuf + w * 512);
    }
}

__device__ __forceinline__ void stage_v_chunk(const ushort* __restrict__ vtb, int kc,
                                              ushort* __restrict__ vbuf, int wid, int lane) {
#pragma unroll
    for (int u = 0; u < 2; ++u) {
        const int w = wid * 2 + u;
        const int rowd = w * 16 + (lane >> 2);
        const int colb = ((lane & 3) * 16) ^ (((rowd >> 1) & 3) << 4);
        gload16(vtb + (size_t)rowd * 2048 + kc + (colb >> 1), vbuf + w * 512);
    }
}

__device__ __forceinline__ void load_k_frags(const ushort* __restrict__ kbuf, int l15, int lhi,
                                             bf16x8 kf[2][4]) {
    const char* kB = (const char*)kbuf;
#pragma unroll
    for (int n2 = 0; n2 < 2; ++n2) {
        const int r = n2 * 16 + l15;
#pragma unroll
        for (int c = 0; c < 4; ++c)
            kf[n2][c] = *(const bf16x8*)(kB + r * 256 + ((lhi * 16 + c * 64) ^ ((r & 7) << 4)));
    }
}

template <bool MASKED>
__device__ __forceinline__ void sums_chunk(const ushort* __restrict__ kbuf, int kc,
                                           int l15, int lhi, int qrow,
                                           const bf16x8* q1f, const bf16x8* q2f,
                                           float& sum1, float& sum2) {
    bf16x8 kf[2][4];
    load_k_frags(kbuf, l15, lhi, kf);
    f32x4 s1[2], s2[2];
#pragma unroll
    for (int n2 = 0; n2 < 2; ++n2) {
        s1[n2] = (f32x4){0.f, 0.f, 0.f, 0.f};
        s2[n2] = (f32x4){0.f, 0.f, 0.f, 0.f};
#pragma unroll
        for (int c = 0; c < 4; ++c) {
            s1[n2] = MFMA16(kf[n2][c], q1f[c], s1[n2]);
            s2[n2] = MFMA16(kf[n2][c], q2f[c], s2[n2]);
        }
    }
    const int kbase = kc + lhi * 4;
#pragma unroll
    for (int n2 = 0; n2 < 2; ++n2)
#pragma unroll
        for (int r = 0; r < 4; ++r) {
            float e1 = __expf(s1[n2][r] * ATTN_SCALE);
            float e2 = __expf(s2[n2][r] * ATTN_SCALE);
            if (MASKED) {
                bool ok = (kbase + n2 * 16 + r) <= qrow;
                e1 = ok ? e1 : 0.f;
                e2 = ok ? e2 : 0.f;
            }
            sum1 += e1;
            sum2 += e2;
        }
}

__global__ __launch_bounds__(256) void attn_sums_k(const ushort* __restrict__ qkv,
                                                   float* __restrict__ sums) {
    __shared__ ushort Kbuf[2 * 4096];
    const int bid = blockIdx.x;
    const int strip = 127 - (bid >> 3);  // longest-first
    const int cs = (bid >> 2) & 1;
    const int hg = bid & 3;
    const int q0 = strip << 4;
    const int lane = threadIdx.x & 63, wid = threadIdx.x >> 6;
    const int h = hg * 4 + wid;
    const int l15 = lane & 15, lhi = lane >> 4;
    const int qrow = q0 + l15;
    const ushort* kb = qkv + 4096;

    bf16x8 q1f[4], q2f[4];
    {
        size_t base = (size_t)qrow * LDQ + h * 128 + lhi * 8;
#pragma unroll
        for (int c = 0; c < 4; ++c) {
            q1f[c] = *(const bf16x8*)(qkv + base + c * 32);
            q2f[c] = *(const bf16x8*)(qkv + base + 2048 + c * 32);
        }
    }

    const int nchunk = (strip >> 1) + 1;
    const int ndiag = nchunk - 1;
    const int nch = (nchunk - cs + 1) >> 1;  // chunks with parity cs

    float sum1 = 0.f, sum2 = 0.f;
    if (nch > 0) stage_k_chunk(kb, cs * 32, Kbuf, wid, lane);
    __syncthreads();
    for (int i = 0; i < nch; ++i) {
        const int ch = cs + 2 * i, kc = ch << 5;
        if (i + 1 < nch) stage_k_chunk(kb, kc + 64, Kbuf + ((i + 1) & 1) * 4096, wid, lane);
        const ushort* kcur = Kbuf + (i & 1) * 4096;
        if (ch == ndiag)
            sums_chunk<true>(kcur, kc, l15, lhi, qrow, q1f, q2f, sum1, sum2);
        else
            sums_chunk<false>(kcur, kc, l15, lhi, qrow, q1f, q2f, sum1, sum2);
        __syncthreads();
    }

    sum1 += __shfl_xor(sum1, 16);
    sum1 += __shfl_xor(sum1, 32);
    sum2 += __shfl_xor(sum2, 16);
    sum2 += __shfl_xor(sum2, 32);

    if (lhi == 0) {
        sums[(size_t)((cs * 2 + 0) * 16 + h) * 2048 + qrow] = sum1;
        sums[(size_t)((cs * 2 + 1) * 16 + h) * 2048 + qrow] = sum2;
    }
}

template <bool MASKED>
__device__ __forceinline__ void pv_chunk(const ushort* __restrict__ kbuf, const ushort* __restrict__ vbuf,
                                         int kc, ushort* __restrict__ Pb,
                                         int l15, int lhi, int qrow,
                                         const bf16x8* q1f, const bf16x8* q2f,
                                         float c1, float c2, f32x4* o) {
    bf16x8 kf[2][4];
    load_k_frags(kbuf, l15, lhi, kf);
    bf16x8 vf[8];
    const char* vB = (const char*)vbuf;
#pragma unroll
    for (int dt = 0; dt < 8; ++dt) {
        const int d = dt * 16 + l15;
        vf[dt] = *(const bf16x8*)(vB + d * 64 + ((lhi * 16) ^ (((d >> 1) & 3) << 4)));
    }
    f32x4 s1[2], s2[2];
#pragma unroll
    for (int n2 = 0; n2 < 2; ++n2) {
        s1[n2] = (f32x4){0.f, 0.f, 0.f, 0.f};
        s2[n2] = (f32x4){0.f, 0.f, 0.f, 0.f};
#pragma unroll
        for (int c = 0; c < 4; ++c) {
            s1[n2] = MFMA16(kf[n2][c], q1f[c], s1[n2]);
            s2[n2] = MFMA16(kf[n2][c], q2f[c], s2[n2]);
        }
    }
    const int kbase = kc + lhi * 4;
#pragma unroll
    for (int n2 = 0; n2 < 2; ++n2) {
        float p[4];
#pragma unroll
        for (int r = 0; r < 4; ++r) {
            float e1 = __expf(s1[n2][r] * ATTN_SCALE) * c1;
            float e2 = __expf(s2[n2][r] * ATTN_SCALE) * c2;
            float pv = fmaxf(e1 - e2, 0.f);
            if (MASKED) pv = ((kbase + n2 * 16 + r) <= qrow) ? pv : 0.f;
            p[r] = pv;
        }
        uint2 w;
        w.x = (unsigned int)f2bf(p[0]) | ((unsigned int)f2bf(p[1]) << 16);
        w.y = (unsigned int)f2bf(p[2]) | ((unsigned int)f2bf(p[3]) << 16);
        *(uint2*)(Pb + l15 * 40 + n2 * 16 + lhi * 4) = w;
    }
    // per-wave private P region: only lgkmcnt ordering needed (keeps vmcnt prefetch in flight)
    asm volatile("s_waitcnt lgkmcnt(0)" ::: "memory");
    bf16x8 pf = *(const bf16x8*)(Pb + l15 * 40 + lhi * 8);
#pragma unroll
    for (int dt = 0; dt < 8; ++dt)
        o[dt] = MFMA16(pf, vf[dt], o[dt]);
}

__global__ __launch_bounds__(256) void attn_pv_k(const ushort* __restrict__ qkv,
                                                 const ushort* __restrict__ vtb,
                                                 const float* __restrict__ sums,
                                                 ushort* __restrict__ op0,
                                                 ushort* __restrict__ op1) {
    __shared__ ushort Kbuf[2 * 4096];
    __shared__ ushort Vbuf[2 * 4096];
    __shared__ ushort P[4][2][16][40];
    const int bid = blockIdx.x;
    const int strip = 127 - (bid >> 3);
    const int cs = (bid >> 2) & 1;
    const int hg = bid & 3;
    const int q0 = strip << 4;
    const int lane = threadIdx.x & 63, wid = threadIdx.x >> 6;
    const int h = hg * 4 + wid;
    const int l15 = lane & 15, lhi = lane >> 4;
    const int qrow = q0 + l15;
    const ushort* kb = qkv + 4096;

    bf16x8 q1f[4], q2f[4];
    {
        size_t base = (size_t)qrow * LDQ + h * 128 + lhi * 8;
#pragma unroll
        for (int c = 0; c < 4; ++c) {
            q1f[c] = *(const bf16x8*)(qkv + base + c * 32);
            q2f[c] = *(const bf16x8*)(qkv + base + 2048 + c * 32);
        }
    }

    const float sum1 = sums[(size_t)(0 * 16 + h) * 2048 + qrow] + sums[(size_t)(2 * 16 + h) * 2048 + qrow];
    const float sum2 = sums[(size_t)(1 * 16 + h) * 2048 + qrow] + sums[(size_t)(3 * 16 + h) * 2048 + qrow];
    const float inv_denom = 1.0f / (0.5f + 1e-8f);
    const float c1 = inv_denom / sum1;
    const float c2 = 0.5f * inv_denom / sum2;

    f32x4 o[8];
#pragma unroll
    for (int dt = 0; dt < 8; ++dt) o[dt] = (f32x4){0.f, 0.f, 0.f, 0.f};

    const int nchunk = (strip >> 1) + 1;
    const int ndiag = nchunk - 1;
    const int nch = (nchunk - cs + 1) >> 1;

    if (nch > 0) {
        stage_k_chunk(kb, cs * 32, Kbuf, wid, lane);
        stage_v_chunk(vtb, cs * 32, Vbuf, wid, lane);
    }
    __syncthreads();
    for (int i = 0; i < nch; ++i) {
        const int ch = cs + 2 * i, kc = ch << 5;
        if (i + 1 < nch) {
            stage_k_chunk(kb, kc + 64, Kbuf + ((i + 1) & 1) * 4096, wid, lane);
            stage_v_chunk(vtb, kc + 64, Vbuf + ((i + 1) & 1) * 4096, wid, lane);
        }
        const ushort* kcur = Kbuf + (i & 1) * 4096;
        const ushort* vcur = Vbuf + (i & 1) * 4096;
        ushort* Pb = &P[wid][i & 1][0][0];
        if (ch == ndiag)
            pv_chunk<true>(kcur, vcur, kc, Pb, l15, lhi, qrow, q1f, q2f, c1, c2, o);
        else
            pv_chunk<false>(kcur, vcur, kc, Pb, l15, lhi, qrow, q1f, q2f, c1, c2, o);
        __syncthreads();
    }

    ushort* op = cs ? op1 : op0;
#pragma unroll
    for (int dt = 0; dt < 8; ++dt)
#pragma unroll
        for (int r = 0; r < 4; ++r)
            op[(size_t)(q0 + lhi * 4 + r) * 2048 + h * 128 + dt * 16 + l15] = f2bf(o[dt][r]);
}

// ---------------- combine partial O halves: aob = bf16(op0 + op1) ----------------
__device__ __forceinline__ unsigned int addbf2(unsigned int a, unsigned int b) {
    float alo = bf2f((ushort)a), ahi = bf2f((ushort)(a >> 16));
    float blo = bf2f((ushort)b), bhi = bf2f((ushort)(b >> 16));
    return (unsigned int)f2bf(alo + blo) | ((unsigned int)f2bf(ahi + bhi) << 16);
}
__global__ void combine_k(const ushort* __restrict__ o0, const ushort* __restrict__ o1,
                          ushort* __restrict__ out, int n8) {
    int i = blockIdx.x * blockDim.x + threadIdx.x;
    if (i >= n8) return;
    uint4 a = ((const uint4*)o0)[i];
    uint4 b = ((const uint4*)o1)[i];
    uint4 c;
    c.x = addbf2(a.x, b.x);
    c.y = addbf2(a.y, b.y);
    c.z = addbf2(a.z, b.z);
    c.w = addbf2(a.w, b.w);
    ((uint4*)out)[i] = c;
}

extern "C" void kernel_launch(void* const* d_in, const int* in_sizes, int n_in,
                              void* d_out, int out_size, void* d_ws, size_t ws_size,
                              hipStream_t stream) {
    const int S = 2048, HID = 2048;

    const float* x = (const float*)d_in[0];
    const float* fcos = (const float*)d_in[1];
    const float* fsin = (const float*)d_in[2];
    // d_in[3] = mask (causal, implicit)
    const float* q1w = (const float*)d_in[4];
    const float* q2w = (const float*)d_in[5];
    const float* kw = (const float*)d_in[6];
    const float* vw = (const float*)d_in[7];
    const float* ow = (const float*)d_in[8];

    ushort* xb = (ushort*)d_ws;                        // 8MB; reused as opart0
    ushort* btq = xb + (size_t)4194304;                // fused Bt: w1t|w2t|wkt|wvt (17MB)
    ushort* w1t = btq;                                 //   reused as opart1
    ushort* w2t = btq + (size_t)2048 * 2048;           //   reused as aob
    ushort* wkt = btq + (size_t)4096 * 2048;
    ushort* wvt = btq + (size_t)4224 * 2048;
    ushort* wot = btq + (size_t)8912896;               // 8MB
    ushort* qkvb = wot + (size_t)4194304;              // 17MB
    ushort* vtb = qkvb + (size_t)8912896;              // 0.5MB
    float* sums = (float*)(vtb + (size_t)262144);      // 0.5MB
    ushort* opart0 = xb;
    ushort* opart1 = w1t;
    ushort* aob = w2t;

    // 1. convert x -> bf16
    cvt_f32_bf16_k<<<dim3(4096), dim3(256), 0, stream>>>(x, xb, S * HID / 4);

    // 2. transpose+convert weights into fused Bt and wot
    tpc_f32_bf16_k<<<dim3(64, 64), dim3(256), 0, stream>>>(q1w, w1t, HID, 2048);
    tpc_f32_bf16_k<<<dim3(64, 64), dim3(256), 0, stream>>>(q2w, w2t, HID, 2048);
    tpc_f32_bf16_k<<<dim3(4, 64), dim3(256), 0, stream>>>(kw, wkt, HID, 128);
    tpc_f32_bf16_k<<<dim3(4, 64), dim3(256), 0, stream>>>(vw, wvt, HID, 128);
    tpc_f32_bf16_k<<<dim3(64, 64), dim3(256), 0, stream>>>(ow, wot, 2048, HID);

    // 3. fused QKV projection: qkvb[2048][4352] = xb @ btq^T
    gemm_glds_k<<<dim3(16, 34), dim3(256), 0, stream>>>(xb, HID, btq, HID, qkvb, LDQ, S, LDQ, HID, 1);

    // 4. fused RoPE over q1|q2|k head-slots
    rope_k<<<dim3(16896), dim3(256), 0, stream>>>(qkvb, fcos, fsin);

    // 5. V -> Vt [128][2048]
    tp_bf16_k<<<dim3(4, 64), dim3(256), 0, stream>>>(qkvb + 4224, LDQ, vtb, S, 128);

    // 6. attention pass 1 (exp-sums): 128 strips x 2 cs x 4 head-groups, 4 waves/block
    attn_sums_k<<<dim3(1024), dim3(256), 0, stream>>>(qkvb, sums);

    // 7. attention pass 2 (PV partials)
    attn_pv_k<<<dim3(1024), dim3(256), 0, stream>>>(qkvb, vtb, sums, opart0, opart1);

    // 8. combine halves -> aob
    combine_k<<<dim3(2048), dim3(256), 0, stream>>>(opart0, opart1, aob, S * HID / 8);

    // 9. output projection (f32 out)
    gemm_glds_k<<<dim3(16, 16), dim3(256), 0, stream>>>(aob, HID, wot, HID, (float*)d_out, HID, S, HID, HID, 0);
}

// Round 5
// 204.101 us; speedup vs baseline: 3.7937x; 1.1764x over previous
//
#include <hip/hip_runtime.h>
#include <hip/hip_bf16.h>

typedef __attribute__((ext_vector_type(8))) short bf16x8;
typedef __attribute__((ext_vector_type(4))) float f32x4;

#define MFMA16(a, b, c) __builtin_amdgcn_mfma_f32_16x16x32_bf16((a), (b), (c), 0, 0, 0)

#define ATTN_SCALE 0.08838834764831845f  // 1/sqrt(128)
#define LDQ 4352                          // fused qkv row stride (2048+2048+128+128)

__device__ __forceinline__ ushort f2bf(float f) {
    unsigned int x = __float_as_uint(f);
    x += 0x7fffu + ((x >> 16) & 1u);
    return (ushort)(x >> 16);
}
__device__ __forceinline__ float bf2f(ushort u) {
    return __uint_as_float(((unsigned int)u) << 16);
}

__device__ __forceinline__ void gload16(const ushort* g, ushort* l) {
    __builtin_amdgcn_global_load_lds((const __attribute__((address_space(1))) unsigned int*)g,
                                     (__attribute__((address_space(3))) unsigned int*)l, 16, 0, 0);
}

// ---------------- fused preprocessing: cvt(x) + 5 weight transposes ----------------
// bid [0,4096): cvt x f32->bf16 (float4 granularity)
// bid [4096,16896): 32x32 transpose+convert tiles for q1w,q2w,ow (64x64 tiles each), kw,vw (4x64)
__global__ __launch_bounds__(256) void prep_k(const float* __restrict__ x, ushort* __restrict__ xb,
                                              const float* __restrict__ q1w, const float* __restrict__ q2w,
                                              const float* __restrict__ kw, const float* __restrict__ vw,
                                              const float* __restrict__ ow,
                                              ushort* __restrict__ w1t, ushort* __restrict__ w2t,
                                              ushort* __restrict__ wkt, ushort* __restrict__ wvt,
                                              ushort* __restrict__ wot) {
    int bid = blockIdx.x;
    if (bid < 4096) {
        int i = bid * 256 + threadIdx.x;
        float4 v = ((const float4*)x)[i];
        ushort4 u;
        u.x = f2bf(v.x); u.y = f2bf(v.y); u.z = f2bf(v.z); u.w = f2bf(v.w);
        ((ushort4*)xb)[i] = u;
        return;
    }
    bid -= 4096;
    const float* in;
    ushort* out;
    int C, TX;
    if (bid < 4096) { in = q1w; out = w1t; C = 2048; TX = 64; }
    else if (bid < 8192) { bid -= 4096; in = q2w; out = w2t; C = 2048; TX = 64; }
    else if (bid < 12288) { bid -= 8192; in = ow; out = wot; C = 2048; TX = 64; }
    else if (bid < 12544) { bid -= 12288; in = kw; out = wkt; C = 128; TX = 4; }
    else { bid -= 12544; in = vw; out = wvt; C = 128; TX = 4; }
    __shared__ ushort t[32][33];
    const int c0 = (bid % TX) * 32, r0 = (bid / TX) * 32;
    const int lx = threadIdx.x & 31, ly = threadIdx.x >> 5;
#pragma unroll
    for (int i = 0; i < 4; ++i)
        t[ly + i * 8][lx] = f2bf(in[(size_t)(r0 + ly + i * 8) * C + c0 + lx]);
    __syncthreads();
#pragma unroll
    for (int i = 0; i < 4; ++i)
        out[(size_t)(c0 + ly + i * 8) * 2048 + r0 + lx] = t[lx][ly + i * 8];
}

// ---------------- fused RoPE (q1|q2|k slots) + V transpose ----------------
__global__ __launch_bounds__(256) void rope_vt_k(ushort* __restrict__ qkv, const float* __restrict__ cs,
                                                 const float* __restrict__ sn, ushort* __restrict__ vtb) {
    int bid = blockIdx.x;
    if (bid < 16896) {
        int i = bid * 256 + threadIdx.x;  // over S*33*64
        int d = i & 63;
        int rest = i >> 6;
        int s = rest / 33;
        int h = rest - s * 33;
        size_t base = (size_t)s * LDQ + h * 128;
        float t0 = bf2f(qkv[base + d]);
        float t1 = bf2f(qkv[base + d + 64]);
        float cA = cs[s * 128 + d], cB = cs[s * 128 + d + 64];
        float sA = sn[s * 128 + d], sB = sn[s * 128 + d + 64];
        qkv[base + d] = f2bf(t0 * cA - t1 * sA);
        qkv[base + d + 64] = f2bf(t1 * cB + t0 * sB);
        return;
    }
    bid -= 16896;  // V transpose: qkv cols [4224,4352) over 2048 rows -> vtb[128][2048]
    __shared__ ushort t[32][33];
    const ushort* in = qkv + 4224;
    const int c0 = (bid & 3) * 32, r0 = (bid >> 2) * 32;
    const int lx = threadIdx.x & 31, ly = threadIdx.x >> 5;
#pragma unroll
    for (int i = 0; i < 4; ++i)
        t[ly + i * 8][lx] = in[(size_t)(r0 + ly + i * 8) * LDQ + c0 + lx];
    __syncthreads();
#pragma unroll
    for (int i = 0; i < 4; ++i)
        vtb[(size_t)(c0 + ly + i * 8) * 2048 + r0 + lx] = t[lx][ly + i * 8];
}

// ---------------- bf16 GEMM: double-buffered global_load_lds, XOR-swizzled LDS ----------------
// C[.][ldc] = A[.][lda] @ Bt[.][ldb]^T. 128x128 tile, BK=32, 4 waves (2x2).
// LDS tiles [128 rows][32 cols bf16] = 64B rows; slot(16B) swizzle: slot ^= (row>>1)&3
// (pre-swizzled global source + swizzled ds_read; gload_lds dest stays linear — rule #21).
// 1D grid, bijectively XCD-swizzled (gridDim.x % 8 == 0).
__global__ __launch_bounds__(256) void gemm_glds_k(const ushort* __restrict__ A, int lda,
                                                   const ushort* __restrict__ Bt, int ldb,
                                                   void* __restrict__ C, int ldc,
                                                   int K, int nbx, int cbf) {
    __shared__ ushort As[2][128 * 32];
    __shared__ ushort Bs[2][128 * 32];
    const int tid = threadIdx.x;
    const int lane = tid & 63, wid = tid >> 6;
    const int cpx = (int)gridDim.x >> 3;
    const int swz = ((int)blockIdx.x & 7) * cpx + ((int)blockIdx.x >> 3);
    const int m0 = (swz % nbx) * 128, n0 = (swz / nbx) * 128;
    const int wr = wid >> 1, wc = wid & 1;
    const int l15 = lane & 15, lhi = lane >> 4;

    // staging: 8 segments of 16 rows per tile; wave stages segs {2w,2w+1} of A and B.
    // lane covers row seg*16+(lane>>2), linear slot lane&3; source col pre-swizzled.
    const int srow0 = wid * 32 + (lane >> 2);
    const int srow1 = srow0 + 16;
    const int scol = (((lane & 3) ^ ((lane >> 3) & 3)) << 3);  // elements (row>>1)&3 == (lane>>3)&3
    const ushort* gA0 = A + (size_t)(m0 + srow0) * lda + scol;
    const ushort* gA1 = A + (size_t)(m0 + srow1) * lda + scol;
    const ushort* gB0 = Bt + (size_t)(n0 + srow0) * ldb + scol;
    const ushort* gB1 = Bt + (size_t)(n0 + srow1) * ldb + scol;
    const int seg0 = (wid * 2 + 0) * 512, seg1 = (wid * 2 + 1) * 512;

    f32x4 acc[4][4];
#pragma unroll
    for (int m = 0; m < 4; ++m)
#pragma unroll
        for (int n = 0; n < 4; ++n) acc[m][n] = (f32x4){0.f, 0.f, 0.f, 0.f};

    // fragment-read swizzle: row = {wr|wc}*64 + m*16 + l15 -> (row>>1)&3 == (l15>>1)&3
    const int rsw = ((l15 >> 1) & 3) << 4;
    const int fcol = (lhi << 4) ^ rsw;  // byte offset within 64B row

    // prologue: stage k=0 into buf 0
    gload16(gA0, &As[0][seg0]);
    gload16(gA1, &As[0][seg1]);
    gload16(gB0, &Bs[0][seg0]);
    gload16(gB1, &Bs[0][seg1]);
    __syncthreads();

    int cur = 0;
    for (int k0 = 0; k0 < K; k0 += 32) {
        if (k0 + 32 < K) {  // prefetch next tile into buf cur^1 (latency hides under compute)
            gload16(gA0 + k0 + 32, &As[cur ^ 1][seg0]);
            gload16(gA1 + k0 + 32, &As[cur ^ 1][seg1]);
            gload16(gB0 + k0 + 32, &Bs[cur ^ 1][seg0]);
            gload16(gB1 + k0 + 32, &Bs[cur ^ 1][seg1]);
        }
        const char* aB = (const char*)As[cur];
        const char* bB = (const char*)Bs[cur];
        bf16x8 af[4], bfr[4];
#pragma unroll
        for (int m = 0; m < 4; ++m)
            af[m] = *(const bf16x8*)(aB + (wr * 64 + m * 16 + l15) * 64 + fcol);
#pragma unroll
        for (int n = 0; n < 4; ++n)
            bfr[n] = *(const bf16x8*)(bB + (wc * 64 + n * 16 + l15) * 64 + fcol);
#pragma unroll
        for (int m = 0; m < 4; ++m)
#pragma unroll
            for (int n = 0; n < 4; ++n)
                acc[m][n] = MFMA16(af[m], bfr[n], acc[m][n]);
        __syncthreads();  // drains vmcnt(0) (prefetch landed) + lgkm; all waves done with cur
        cur ^= 1;
    }

#pragma unroll
    for (int m = 0; m < 4; ++m) {
        const int rb = m0 + wr * 64 + m * 16 + lhi * 4;
#pragma unroll
        for (int n = 0; n < 4; ++n) {
            const int col = n0 + wc * 64 + n * 16 + l15;
#pragma unroll
            for (int r = 0; r < 4; ++r) {
                if (cbf)
                    ((ushort*)C)[(size_t)(rb + r) * ldc + col] = f2bf(acc[m][n][r]);
                else
                    ((float*)C)[(size_t)(rb + r) * ldc + col] = acc[m][n][r];
            }
        }
    }
}

// ---------------- differential MQA attention ----------------
// Blocks of 4 waves = 4 heads sharing one 16-row q-strip; K (and V) chunks staged
// once per block into double-buffered, XOR-swizzled LDS (global_load_lds, linear
// dest + pre-swizzled global source + swizzled read — rule #21).
// K tile [32][128] bf16 (256B rows): byte ^= (row&7)<<4.
// V tile [128][32] bf16 (64B rows):  byte ^= ((row>>1)&3)<<4.

__device__ __forceinline__ void stage_k_chunk(const ushort* __restrict__ kb, int kc,
                                              ushort* __restrict__ kbuf, int wid, int lane) {
#pragma unroll
    for (int u = 0; u < 2; ++u) {
        const int w = wid * 2 + u;
        const int row = w * 4 + (lane >> 4);
        const int colb = ((lane & 15) * 16) ^ ((row & 7) << 4);
        gload16(kb + (size_t)(kc + row) * LDQ + (colb >> 1), kbuf + w * 512);
    }
}

__device__ __forceinline__ void stage_v_chunk(const ushort* __restrict__ vtb, int kc,
                                              ushort* __restrict__ vbuf, int wid, int lane) {
#pragma unroll
    for (int u = 0; u < 2; ++u) {
        const int w = wid * 2 + u;
        const int rowd = w * 16 + (lane >> 2);
        const int colb = ((lane & 3) * 16) ^ (((rowd >> 1) & 3) << 4);
        gload16(vtb + (size_t)rowd * 2048 + kc + (colb >> 1), vbuf + w * 512);
    }
}

__device__ __forceinline__ void load_k_frags(const ushort* __restrict__ kbuf, int l15, int lhi,
                                             bf16x8 kf[2][4]) {
    const char* kB = (const char*)kbuf;
#pragma unroll
    for (int n2 = 0; n2 < 2; ++n2) {
        const int r = n2 * 16 + l15;
#pragma unroll
        for (int c = 0; c < 4; ++c)
            kf[n2][c] = *(const bf16x8*)(kB + r * 256 + ((lhi * 16 + c * 64) ^ ((r & 7) << 4)));
    }
}

template <bool MASKED>
__device__ __forceinline__ void sums_chunk(const ushort* __restrict__ kbuf, int kc,
                                           int l15, int lhi, int qrow,
                                           const bf16x8* q1f, const bf16x8* q2f,
                                           float& sum1, float& sum2) {
    bf16x8 kf[2][4];
    load_k_frags(kbuf, l15, lhi, kf);
    f32x4 s1[2], s2[2];
#pragma unroll
    for (int n2 = 0; n2 < 2; ++n2) {
        s1[n2] = (f32x4){0.f, 0.f, 0.f, 0.f};
        s2[n2] = (f32x4){0.f, 0.f, 0.f, 0.f};
#pragma unroll
        for (int c = 0; c < 4; ++c) {
            s1[n2] = MFMA16(kf[n2][c], q1f[c], s1[n2]);
            s2[n2] = MFMA16(kf[n2][c], q2f[c], s2[n2]);
        }
    }
    const int kbase = kc + lhi * 4;
#pragma unroll
    for (int n2 = 0; n2 < 2; ++n2)
#pragma unroll
        for (int r = 0; r < 4; ++r) {
            float e1 = __expf(s1[n2][r] * ATTN_SCALE);
            float e2 = __expf(s2[n2][r] * ATTN_SCALE);
            if (MASKED) {
                bool ok = (kbase + n2 * 16 + r) <= qrow;
                e1 = ok ? e1 : 0.f;
                e2 = ok ? e2 : 0.f;
            }
            sum1 += e1;
            sum2 += e2;
        }
}

__global__ __launch_bounds__(256) void attn_sums_k(const ushort* __restrict__ qkv,
                                                   float* __restrict__ sums) {
    __shared__ ushort Kbuf[2 * 4096];
    const int bid = blockIdx.x;
    const int strip = 127 - (bid >> 3);  // longest-first
    const int cs = (bid >> 2) & 1;
    const int hg = bid & 3;
    const int q0 = strip << 4;
    const int lane = threadIdx.x & 63, wid = threadIdx.x >> 6;
    const int h = hg * 4 + wid;
    const int l15 = lane & 15, lhi = lane >> 4;
    const int qrow = q0 + l15;
    const ushort* kb = qkv + 4096;

    bf16x8 q1f[4], q2f[4];
    {
        size_t base = (size_t)qrow * LDQ + h * 128 + lhi * 8;
#pragma unroll
        for (int c = 0; c < 4; ++c) {
            q1f[c] = *(const bf16x8*)(qkv + base + c * 32);
            q2f[c] = *(const bf16x8*)(qkv + base + 2048 + c * 32);
        }
    }

    const int nchunk = (strip >> 1) + 1;
    const int ndiag = nchunk - 1;
    const int nch = (nchunk - cs + 1) >> 1;  // chunks with parity cs

    float sum1 = 0.f, sum2 = 0.f;
    if (nch > 0) stage_k_chunk(kb, cs * 32, Kbuf, wid, lane);
    __syncthreads();
    for (int i = 0; i < nch; ++i) {
        const int ch = cs + 2 * i, kc = ch << 5;
        if (i + 1 < nch) stage_k_chunk(kb, kc + 64, Kbuf + ((i + 1) & 1) * 4096, wid, lane);
        const ushort* kcur = Kbuf + (i & 1) * 4096;
        if (ch == ndiag)
            sums_chunk<true>(kcur, kc, l15, lhi, qrow, q1f, q2f, sum1, sum2);
        else
            sums_chunk<false>(kcur, kc, l15, lhi, qrow, q1f, q2f, sum1, sum2);
        __syncthreads();
    }

    sum1 += __shfl_xor(sum1, 16);
    sum1 += __shfl_xor(sum1, 32);
    sum2 += __shfl_xor(sum2, 16);
    sum2 += __shfl_xor(sum2, 32);

    if (lhi == 0) {
        sums[(size_t)((cs * 2 + 0) * 16 + h) * 2048 + qrow] = sum1;
        sums[(size_t)((cs * 2 + 1) * 16 + h) * 2048 + qrow] = sum2;
    }
}

template <bool MASKED>
__device__ __forceinline__ void pv_chunk(const ushort* __restrict__ kbuf, const ushort* __restrict__ vbuf,
                                         int kc, ushort* __restrict__ Pb,
                                         int l15, int lhi, int qrow,
                                         const bf16x8* q1f, const bf16x8* q2f,
                                         float c1, float c2, f32x4* o) {
    bf16x8 kf[2][4];
    load_k_frags(kbuf, l15, lhi, kf);
    bf16x8 vf[8];
    const char* vB = (const char*)vbuf;
#pragma unroll
    for (int dt = 0; dt < 8; ++dt) {
        const int d = dt * 16 + l15;
        vf[dt] = *(const bf16x8*)(vB + d * 64 + ((lhi * 16) ^ (((d >> 1) & 3) << 4)));
    }
    f32x4 s1[2], s2[2];
#pragma unroll
    for (int n2 = 0; n2 < 2; ++n2) {
        s1[n2] = (f32x4){0.f, 0.f, 0.f, 0.f};
        s2[n2] = (f32x4){0.f, 0.f, 0.f, 0.f};
#pragma unroll
        for (int c = 0; c < 4; ++c) {
            s1[n2] = MFMA16(kf[n2][c], q1f[c], s1[n2]);
            s2[n2] = MFMA16(kf[n2][c], q2f[c], s2[n2]);
        }
    }
    const int kbase = kc + lhi * 4;
#pragma unroll
    for (int n2 = 0; n2 < 2; ++n2) {
        float p[4];
#pragma unroll
        for (int r = 0; r < 4; ++r) {
            float e1 = __expf(s1[n2][r] * ATTN_SCALE) * c1;
            float e2 = __expf(s2[n2][r] * ATTN_SCALE) * c2;
            float pv = fmaxf(e1 - e2, 0.f);
            if (MASKED) pv = ((kbase + n2 * 16 + r) <= qrow) ? pv : 0.f;
            p[r] = pv;
        }
        uint2 w;
        w.x = (unsigned int)f2bf(p[0]) | ((unsigned int)f2bf(p[1]) << 16);
        w.y = (unsigned int)f2bf(p[2]) | ((unsigned int)f2bf(p[3]) << 16);
        *(uint2*)(Pb + l15 * 40 + n2 * 16 + lhi * 4) = w;
    }
    // per-wave private P region: only lgkmcnt ordering needed (keeps vmcnt prefetch in flight)
    asm volatile("s_waitcnt lgkmcnt(0)" ::: "memory");
    bf16x8 pf = *(const bf16x8*)(Pb + l15 * 40 + lhi * 8);
#pragma unroll
    for (int dt = 0; dt < 8; ++dt)
        o[dt] = MFMA16(pf, vf[dt], o[dt]);
}

__global__ __launch_bounds__(256) void attn_pv_k(const ushort* __restrict__ qkv,
                                                 const ushort* __restrict__ vtb,
                                                 const float* __restrict__ sums,
                                                 ushort* __restrict__ op0,
                                                 ushort* __restrict__ op1) {
    __shared__ ushort Kbuf[2 * 4096];
    __shared__ ushort Vbuf[2 * 4096];
    __shared__ ushort P[4][2][16][40];
    const int bid = blockIdx.x;
    const int strip = 127 - (bid >> 3);
    const int cs = (bid >> 2) & 1;
    const int hg = bid & 3;
    const int q0 = strip << 4;
    const int lane = threadIdx.x & 63, wid = threadIdx.x >> 6;
    const int h = hg * 4 + wid;
    const int l15 = lane & 15, lhi = lane >> 4;
    const int qrow = q0 + l15;
    const ushort* kb = qkv + 4096;

    bf16x8 q1f[4], q2f[4];
    {
        size_t base = (size_t)qrow * LDQ + h * 128 + lhi * 8;
#pragma unroll
        for (int c = 0; c < 4; ++c) {
            q1f[c] = *(const bf16x8*)(qkv + base + c * 32);
            q2f[c] = *(const bf16x8*)(qkv + base + 2048 + c * 32);
        }
    }

    const float sum1 = sums[(size_t)(0 * 16 + h) * 2048 + qrow] + sums[(size_t)(2 * 16 + h) * 2048 + qrow];
    const float sum2 = sums[(size_t)(1 * 16 + h) * 2048 + qrow] + sums[(size_t)(3 * 16 + h) * 2048 + qrow];
    const float inv_denom = 1.0f / (0.5f + 1e-8f);
    const float c1 = inv_denom / sum1;
    const float c2 = 0.5f * inv_denom / sum2;

    f32x4 o[8];
#pragma unroll
    for (int dt = 0; dt < 8; ++dt) o[dt] = (f32x4){0.f, 0.f, 0.f, 0.f};

    const int nchunk = (strip >> 1) + 1;
    const int ndiag = nchunk - 1;
    const int nch = (nchunk - cs + 1) >> 1;

    if (nch > 0) {
        stage_k_chunk(kb, cs * 32, Kbuf, wid, lane);
        stage_v_chunk(vtb, cs * 32, Vbuf, wid, lane);
    }
    __syncthreads();
    for (int i = 0; i < nch; ++i) {
        const int ch = cs + 2 * i, kc = ch << 5;
        if (i + 1 < nch) {
            stage_k_chunk(kb, kc + 64, Kbuf + ((i + 1) & 1) * 4096, wid, lane);
            stage_v_chunk(vtb, kc + 64, Vbuf + ((i + 1) & 1) * 4096, wid, lane);
        }
        const ushort* kcur = Kbuf + (i & 1) * 4096;
        const ushort* vcur = Vbuf + (i & 1) * 4096;
        ushort* Pb = &P[wid][i & 1][0][0];
        if (ch == ndiag)
            pv_chunk<true>(kcur, vcur, kc, Pb, l15, lhi, qrow, q1f, q2f, c1, c2, o);
        else
            pv_chunk<false>(kcur, vcur, kc, Pb, l15, lhi, qrow, q1f, q2f, c1, c2, o);
        __syncthreads();
    }

    ushort* op = cs ? op1 : op0;
#pragma unroll
    for (int dt = 0; dt < 8; ++dt)
#pragma unroll
        for (int r = 0; r < 4; ++r)
            op[(size_t)(q0 + lhi * 4 + r) * 2048 + h * 128 + dt * 16 + l15] = f2bf(o[dt][r]);
}

// ---------------- combine partial O halves: aob = bf16(op0 + op1) ----------------
__device__ __forceinline__ unsigned int addbf2(unsigned int a, unsigned int b) {
    float alo = bf2f((ushort)a), ahi = bf2f((ushort)(a >> 16));
    float blo = bf2f((ushort)b), bhi = bf2f((ushort)(b >> 16));
    return (unsigned int)f2bf(alo + blo) | ((unsigned int)f2bf(ahi + bhi) << 16);
}
__global__ void combine_k(const ushort* __restrict__ o0, const ushort* __restrict__ o1,
                          ushort* __restrict__ out, int n8) {
    int i = blockIdx.x * blockDim.x + threadIdx.x;
    if (i >= n8) return;
    uint4 a = ((const uint4*)o0)[i];
    uint4 b = ((const uint4*)o1)[i];
    uint4 c;
    c.x = addbf2(a.x, b.x);
    c.y = addbf2(a.y, b.y);
    c.z = addbf2(a.z, b.z);
    c.w = addbf2(a.w, b.w);
    ((uint4*)out)[i] = c;
}

extern "C" void kernel_launch(void* const* d_in, const int* in_sizes, int n_in,
                              void* d_out, int out_size, void* d_ws, size_t ws_size,
                              hipStream_t stream) {
    const int S = 2048, HID = 2048;

    const float* x = (const float*)d_in[0];
    const float* fcos = (const float*)d_in[1];
    const float* fsin = (const float*)d_in[2];
    // d_in[3] = mask (causal, implicit)
    const float* q1w = (const float*)d_in[4];
    const float* q2w = (const float*)d_in[5];
    const float* kw = (const float*)d_in[6];
    const float* vw = (const float*)d_in[7];
    const float* ow = (const float*)d_in[8];

    ushort* xb = (ushort*)d_ws;                        // 8MB; reused as opart0
    ushort* btq = xb + (size_t)4194304;                // fused Bt: w1t|w2t|wkt|wvt (17MB)
    ushort* w1t = btq;                                 //   reused as opart1
    ushort* w2t = btq + (size_t)2048 * 2048;           //   reused as aob
    ushort* wkt = btq + (size_t)4096 * 2048;
    ushort* wvt = btq + (size_t)4224 * 2048;
    ushort* wot = btq + (size_t)8912896;               // 8MB
    ushort* qkvb = wot + (size_t)4194304;              // 17MB
    ushort* vtb = qkvb + (size_t)8912896;              // 0.5MB
    float* sums = (float*)(vtb + (size_t)262144);      // 0.5MB
    ushort* opart0 = xb;
    ushort* opart1 = w1t;
    ushort* aob = w2t;

    // 1. fused preprocessing: cvt(x) + 5 weight transpose/converts
    prep_k<<<dim3(16896), dim3(256), 0, stream>>>(x, xb, q1w, q2w, kw, vw, ow,
                                                  w1t, w2t, wkt, wvt, wot);

    // 2. fused QKV projection: qkvb[2048][4352] = xb @ btq^T (544 blocks, XCD-swizzled)
    gemm_glds_k<<<dim3(544), dim3(256), 0, stream>>>(xb, HID, btq, HID, qkvb, LDQ, HID, 16, 1);

    // 3. fused RoPE (q1|q2|k slots) + V -> Vt [128][2048]
    rope_vt_k<<<dim3(17152), dim3(256), 0, stream>>>(qkvb, fcos, fsin, vtb);

    // 4. attention pass 1 (exp-sums): 128 strips x 2 cs x 4 head-groups, 4 waves/block
    attn_sums_k<<<dim3(1024), dim3(256), 0, stream>>>(qkvb, sums);

    // 5. attention pass 2 (PV partials)
    attn_pv_k<<<dim3(1024), dim3(256), 0, stream>>>(qkvb, vtb, sums, opart0, opart1);

    // 6. combine halves -> aob
    combine_k<<<dim3(2048), dim3(256), 0, stream>>>(opart0, opart1, aob, S * HID / 8);

    // 7. output projection (f32 out, 256 blocks XCD-swizzled)
    gemm_glds_k<<<dim3(256), dim3(256), 0, stream>>>(aob, HID, wot, HID, (float*)d_out, HID, HID, 16, 0);
}

// Round 6
// 195.953 us; speedup vs baseline: 3.9515x; 1.0416x over previous
//
#include <hip/hip_runtime.h>
#include <hip/hip_bf16.h>

typedef __attribute__((ext_vector_type(8))) short bf16x8;
typedef __attribute__((ext_vector_type(4))) float f32x4;

#define MFMA16(a, b, c) __builtin_amdgcn_mfma_f32_16x16x32_bf16((a), (b), (c), 0, 0, 0)

#define LDQ 4352  // fused qkv row stride (2048+2048+128+128)
// K columns are pre-scaled by 1/sqrt(128)*log2(e) in the QKV GEMM epilogue,
// so attention probabilities are exp2(s) = v_exp_f32(s) directly.
#define KSCALE 0.12751743f

__device__ __forceinline__ ushort f2bf(float f) {
    unsigned int x = __float_as_uint(f);
    x += 0x7fffu + ((x >> 16) & 1u);
    return (ushort)(x >> 16);
}
__device__ __forceinline__ float bf2f(ushort u) {
    return __uint_as_float(((unsigned int)u) << 16);
}
__device__ __forceinline__ float exp2_fast(float x) {
    float r;
    asm("v_exp_f32 %0, %1" : "=v"(r) : "v"(x));
    return r;
}
__device__ __forceinline__ unsigned int cvtpk(float lo, float hi) {
    unsigned int r;
    asm("v_cvt_pk_bf16_f32 %0, %1, %2" : "=v"(r) : "v"(lo), "v"(hi));
    return r;
}

__device__ __forceinline__ void gload16(const ushort* g, ushort* l) {
    __builtin_amdgcn_global_load_lds((const __attribute__((address_space(1))) unsigned int*)g,
                                     (__attribute__((address_space(3))) unsigned int*)l, 16, 0, 0);
}

// ---------------- fused preprocessing: cvt(x) + 5 weight transposes ----------------
__global__ __launch_bounds__(256) void prep_k(const float* __restrict__ x, ushort* __restrict__ xb,
                                              const float* __restrict__ q1w, const float* __restrict__ q2w,
                                              const float* __restrict__ kw, const float* __restrict__ vw,
                                              const float* __restrict__ ow,
                                              ushort* __restrict__ w1t, ushort* __restrict__ w2t,
                                              ushort* __restrict__ wkt, ushort* __restrict__ wvt,
                                              ushort* __restrict__ wot) {
    int bid = blockIdx.x;
    if (bid < 4096) {
        int i = bid * 256 + threadIdx.x;
        float4 v = ((const float4*)x)[i];
        ushort4 u;
        u.x = f2bf(v.x); u.y = f2bf(v.y); u.z = f2bf(v.z); u.w = f2bf(v.w);
        ((ushort4*)xb)[i] = u;
        return;
    }
    bid -= 4096;
    const float* in;
    ushort* out;
    int C, TX;
    if (bid < 4096) { in = q1w; out = w1t; C = 2048; TX = 64; }
    else if (bid < 8192) { bid -= 4096; in = q2w; out = w2t; C = 2048; TX = 64; }
    else if (bid < 12288) { bid -= 8192; in = ow; out = wot; C = 2048; TX = 64; }
    else if (bid < 12544) { bid -= 12288; in = kw; out = wkt; C = 128; TX = 4; }
    else { bid -= 12544; in = vw; out = wvt; C = 128; TX = 4; }
    __shared__ ushort t[32][33];
    const int c0 = (bid % TX) * 32, r0 = (bid / TX) * 32;
    const int lx = threadIdx.x & 31, ly = threadIdx.x >> 5;
#pragma unroll
    for (int i = 0; i < 4; ++i)
        t[ly + i * 8][lx] = f2bf(in[(size_t)(r0 + ly + i * 8) * C + c0 + lx]);
    __syncthreads();
#pragma unroll
    for (int i = 0; i < 4; ++i)
        out[(size_t)(c0 + ly + i * 8) * 2048 + r0 + lx] = t[lx][ly + i * 8];
}

// ---------------- fused RoPE (q1|q2|k slots) + V transpose ----------------
__global__ __launch_bounds__(256) void rope_vt_k(ushort* __restrict__ qkv, const float* __restrict__ cs,
                                                 const float* __restrict__ sn, ushort* __restrict__ vtb) {
    int bid = blockIdx.x;
    if (bid < 16896) {
        int i = bid * 256 + threadIdx.x;  // over S*33*64
        int d = i & 63;
        int rest = i >> 6;
        int s = rest / 33;
        int h = rest - s * 33;
        size_t base = (size_t)s * LDQ + h * 128;
        float t0 = bf2f(qkv[base + d]);
        float t1 = bf2f(qkv[base + d + 64]);
        float cA = cs[s * 128 + d], cB = cs[s * 128 + d + 64];
        float sA = sn[s * 128 + d], sB = sn[s * 128 + d + 64];
        qkv[base + d] = f2bf(t0 * cA - t1 * sA);
        qkv[base + d + 64] = f2bf(t1 * cB + t0 * sB);
        return;
    }
    bid -= 16896;  // V transpose: qkv cols [4224,4352) over 2048 rows -> vtb[128][2048]
    __shared__ ushort t[32][33];
    const ushort* in = qkv + 4224;
    const int c0 = (bid & 3) * 32, r0 = (bid >> 2) * 32;
    const int lx = threadIdx.x & 31, ly = threadIdx.x >> 5;
#pragma unroll
    for (int i = 0; i < 4; ++i)
        t[ly + i * 8][lx] = in[(size_t)(r0 + ly + i * 8) * LDQ + c0 + lx];
    __syncthreads();
#pragma unroll
    for (int i = 0; i < 4; ++i)
        vtb[(size_t)(c0 + ly + i * 8) * 2048 + r0 + lx] = t[lx][ly + i * 8];
}

// ---------------- bf16 GEMM: double-buffered global_load_lds, XOR-swizzled LDS ----------------
// C[.][ldc] = A[.][lda] @ Bt[.][ldb]^T. 128x128 tile, BK=32, 4 waves (2x2).
// kst: col-tile index whose output gets *KSCALE (the K head-slot), or -1.
__global__ __launch_bounds__(256) void gemm_glds_k(const ushort* __restrict__ A, int lda,
                                                   const ushort* __restrict__ Bt, int ldb,
                                                   void* __restrict__ C, int ldc,
                                                   int K, int nbx, int cbf, int kst) {
    __shared__ ushort As[2][128 * 32];
    __shared__ ushort Bs[2][128 * 32];
    const int tid = threadIdx.x;
    const int lane = tid & 63, wid = tid >> 6;
    const int cpx = (int)gridDim.x >> 3;
    const int swz = ((int)blockIdx.x & 7) * cpx + ((int)blockIdx.x >> 3);
    const int nt = swz / nbx;
    const int m0 = (swz % nbx) * 128, n0 = nt * 128;
    const int wr = wid >> 1, wc = wid & 1;
    const int l15 = lane & 15, lhi = lane >> 4;
    const float cscale = (nt == kst) ? KSCALE : 1.0f;

    const int srow0 = wid * 32 + (lane >> 2);
    const int srow1 = srow0 + 16;
    const int scol = (((lane & 3) ^ ((lane >> 3) & 3)) << 3);
    const ushort* gA0 = A + (size_t)(m0 + srow0) * lda + scol;
    const ushort* gA1 = A + (size_t)(m0 + srow1) * lda + scol;
    const ushort* gB0 = Bt + (size_t)(n0 + srow0) * ldb + scol;
    const ushort* gB1 = Bt + (size_t)(n0 + srow1) * ldb + scol;
    const int seg0 = (wid * 2 + 0) * 512, seg1 = (wid * 2 + 1) * 512;

    f32x4 acc[4][4];
#pragma unroll
    for (int m = 0; m < 4; ++m)
#pragma unroll
        for (int n = 0; n < 4; ++n) acc[m][n] = (f32x4){0.f, 0.f, 0.f, 0.f};

    const int rsw = ((l15 >> 1) & 3) << 4;
    const int fcol = (lhi << 4) ^ rsw;

    gload16(gA0, &As[0][seg0]);
    gload16(gA1, &As[0][seg1]);
    gload16(gB0, &Bs[0][seg0]);
    gload16(gB1, &Bs[0][seg1]);
    __syncthreads();

    int cur = 0;
    for (int k0 = 0; k0 < K; k0 += 32) {
        if (k0 + 32 < K) {
            gload16(gA0 + k0 + 32, &As[cur ^ 1][seg0]);
            gload16(gA1 + k0 + 32, &As[cur ^ 1][seg1]);
            gload16(gB0 + k0 + 32, &Bs[cur ^ 1][seg0]);
            gload16(gB1 + k0 + 32, &Bs[cur ^ 1][seg1]);
        }
        const char* aB = (const char*)As[cur];
        const char* bB = (const char*)Bs[cur];
        bf16x8 af[4], bfr[4];
#pragma unroll
        for (int m = 0; m < 4; ++m)
            af[m] = *(const bf16x8*)(aB + (wr * 64 + m * 16 + l15) * 64 + fcol);
#pragma unroll
        for (int n = 0; n < 4; ++n)
            bfr[n] = *(const bf16x8*)(bB + (wc * 64 + n * 16 + l15) * 64 + fcol);
#pragma unroll
        for (int m = 0; m < 4; ++m)
#pragma unroll
            for (int n = 0; n < 4; ++n)
                acc[m][n] = MFMA16(af[m], bfr[n], acc[m][n]);
        __syncthreads();
        cur ^= 1;
    }

#pragma unroll
    for (int m = 0; m < 4; ++m) {
        const int rb = m0 + wr * 64 + m * 16 + lhi * 4;
#pragma unroll
        for (int n = 0; n < 4; ++n) {
            const int col = n0 + wc * 64 + n * 16 + l15;
#pragma unroll
            for (int r = 0; r < 4; ++r) {
                float v = acc[m][n][r] * cscale;
                if (cbf)
                    ((ushort*)C)[(size_t)(rb + r) * ldc + col] = f2bf(v);
                else
                    ((float*)C)[(size_t)(rb + r) * ldc + col] = v;
            }
        }
    }
}

// ---------------- differential MQA attention ----------------
// Blocks of 4 waves = 4 heads sharing one 16-row q-strip; K (and V) chunks staged
// once per block into double-buffered, XOR-swizzled LDS. K arrives pre-scaled so
// probabilities are exp2(s) directly (single v_exp_f32).

__device__ __forceinline__ void stage_k_chunk(const ushort* __restrict__ kb, int kc,
                                              ushort* __restrict__ kbuf, int wid, int lane) {
#pragma unroll
    for (int u = 0; u < 2; ++u) {
        const int w = wid * 2 + u;
        const int row = w * 4 + (lane >> 4);
        const int colb = ((lane & 15) * 16) ^ ((row & 7) << 4);
        gload16(kb + (size_t)(kc + row) * LDQ + (colb >> 1), kbuf + w * 512);
    }
}

__device__ __forceinline__ void stage_v_chunk(const ushort* __restrict__ vtb, int kc,
                                              ushort* __restrict__ vbuf, int wid, int lane) {
#pragma unroll
    for (int u = 0; u < 2; ++u) {
        const int w = wid * 2 + u;
        const int rowd = w * 16 + (lane >> 2);
        const int colb = ((lane & 3) * 16) ^ (((rowd >> 1) & 3) << 4);
        gload16(vtb + (size_t)rowd * 2048 + kc + (colb >> 1), vbuf + w * 512);
    }
}

__device__ __forceinline__ void load_k_frags(const ushort* __restrict__ kbuf, int l15, int lhi,
                                             bf16x8 kf[2][4]) {
    const char* kB = (const char*)kbuf;
#pragma unroll
    for (int n2 = 0; n2 < 2; ++n2) {
        const int r = n2 * 16 + l15;
#pragma unroll
        for (int c = 0; c < 4; ++c)
            kf[n2][c] = *(const bf16x8*)(kB + r * 256 + ((lhi * 16 + c * 64) ^ ((r & 7) << 4)));
    }
}

template <bool MASKED>
__device__ __forceinline__ void sums_chunk(const ushort* __restrict__ kbuf, int kc,
                                           int l15, int lhi, int qrow,
                                           const bf16x8* q1f, const bf16x8* q2f,
                                           float& sum1, float& sum2) {
    bf16x8 kf[2][4];
    load_k_frags(kbuf, l15, lhi, kf);
    f32x4 s1[2], s2[2];
#pragma unroll
    for (int n2 = 0; n2 < 2; ++n2) {
        s1[n2] = (f32x4){0.f, 0.f, 0.f, 0.f};
        s2[n2] = (f32x4){0.f, 0.f, 0.f, 0.f};
#pragma unroll
        for (int c = 0; c < 4; ++c) {
            s1[n2] = MFMA16(kf[n2][c], q1f[c], s1[n2]);
            s2[n2] = MFMA16(kf[n2][c], q2f[c], s2[n2]);
        }
    }
    const int kbase = kc + lhi * 4;
#pragma unroll
    for (int n2 = 0; n2 < 2; ++n2)
#pragma unroll
        for (int r = 0; r < 4; ++r) {
            float e1 = exp2_fast(s1[n2][r]);
            float e2 = exp2_fast(s2[n2][r]);
            if (MASKED) {
                bool ok = (kbase + n2 * 16 + r) <= qrow;
                e1 = ok ? e1 : 0.f;
                e2 = ok ? e2 : 0.f;
            }
            sum1 += e1;
            sum2 += e2;
        }
}

__global__ __launch_bounds__(256) void attn_sums_k(const ushort* __restrict__ qkv,
                                                   float* __restrict__ sums) {
    __shared__ ushort Kbuf[2 * 4096];
    const int bid = blockIdx.x;
    const int strip = 127 - (bid >> 3);  // longest-first
    const int cs = (bid >> 2) & 1;
    const int hg = bid & 3;
    const int q0 = strip << 4;
    const int lane = threadIdx.x & 63, wid = threadIdx.x >> 6;
    const int h = hg * 4 + wid;
    const int l15 = lane & 15, lhi = lane >> 4;
    const int qrow = q0 + l15;
    const ushort* kb = qkv + 4096;

    bf16x8 q1f[4], q2f[4];
    {
        size_t base = (size_t)qrow * LDQ + h * 128 + lhi * 8;
#pragma unroll
        for (int c = 0; c < 4; ++c) {
            q1f[c] = *(const bf16x8*)(qkv + base + c * 32);
            q2f[c] = *(const bf16x8*)(qkv + base + 2048 + c * 32);
        }
    }

    const int nchunk = (strip >> 1) + 1;
    const int ndiag = nchunk - 1;
    const int nch = (nchunk - cs + 1) >> 1;  // chunks with parity cs

    float sum1 = 0.f, sum2 = 0.f;
    if (nch > 0) stage_k_chunk(kb, cs * 32, Kbuf, wid, lane);
    __syncthreads();
    for (int i = 0; i < nch; ++i) {
        const int ch = cs + 2 * i, kc = ch << 5;
        if (i + 1 < nch) stage_k_chunk(kb, kc + 64, Kbuf + ((i + 1) & 1) * 4096, wid, lane);
        const ushort* kcur = Kbuf + (i & 1) * 4096;
        if (ch == ndiag)
            sums_chunk<true>(kcur, kc, l15, lhi, qrow, q1f, q2f, sum1, sum2);
        else
            sums_chunk<false>(kcur, kc, l15, lhi, qrow, q1f, q2f, sum1, sum2);
        __syncthreads();
    }

    sum1 += __shfl_xor(sum1, 16);
    sum1 += __shfl_xor(sum1, 32);
    sum2 += __shfl_xor(sum2, 16);
    sum2 += __shfl_xor(sum2, 32);

    if (lhi == 0) {
        sums[(size_t)((cs * 2 + 0) * 16 + h) * 2048 + qrow] = sum1;
        sums[(size_t)((cs * 2 + 1) * 16 + h) * 2048 + qrow] = sum2;
    }
}

template <bool MASKED>
__device__ __forceinline__ void pv_chunk(const ushort* __restrict__ kbuf, const ushort* __restrict__ vbuf,
                                         int kc, ushort* __restrict__ Pb,
                                         int l15, int lhi, int qrow,
                                         const bf16x8* q1f, const bf16x8* q2f,
                                         float c1, float c2, f32x4* o) {
    bf16x8 kf[2][4];
    load_k_frags(kbuf, l15, lhi, kf);
    bf16x8 vf[8];
    const char* vB = (const char*)vbuf;
#pragma unroll
    for (int dt = 0; dt < 8; ++dt) {
        const int d = dt * 16 + l15;
        vf[dt] = *(const bf16x8*)(vB + d * 64 + ((lhi * 16) ^ (((d >> 1) & 3) << 4)));
    }
    f32x4 s1[2], s2[2];
#pragma unroll
    for (int n2 = 0; n2 < 2; ++n2) {
        s1[n2] = (f32x4){0.f, 0.f, 0.f, 0.f};
        s2[n2] = (f32x4){0.f, 0.f, 0.f, 0.f};
#pragma unroll
        for (int c = 0; c < 4; ++c) {
            s1[n2] = MFMA16(kf[n2][c], q1f[c], s1[n2]);
            s2[n2] = MFMA16(kf[n2][c], q2f[c], s2[n2]);
        }
    }
    const int kbase = kc + lhi * 4;
#pragma unroll
    for (int n2 = 0; n2 < 2; ++n2) {
        float p[4];
#pragma unroll
        for (int r = 0; r < 4; ++r) {
            float e1 = exp2_fast(s1[n2][r]) * c1;
            float e2 = exp2_fast(s2[n2][r]) * c2;
            float pv = fmaxf(e1 - e2, 0.f);
            if (MASKED) pv = ((kbase + n2 * 16 + r) <= qrow) ? pv : 0.f;
            p[r] = pv;
        }
        uint2 w;
        w.x = cvtpk(p[0], p[1]);
        w.y = cvtpk(p[2], p[3]);
        *(uint2*)(Pb + l15 * 40 + n2 * 16 + lhi * 4) = w;
    }
    // per-wave private P region; same-wave DS ops are FIFO -> only lgkm drain needed
    asm volatile("s_waitcnt lgkmcnt(0)" ::: "memory");
    bf16x8 pf = *(const bf16x8*)(Pb + l15 * 40 + lhi * 8);
#pragma unroll
    for (int dt = 0; dt < 8; ++dt)
        o[dt] = MFMA16(pf, vf[dt], o[dt]);
}

__global__ __launch_bounds__(256) void attn_pv_k(const ushort* __restrict__ qkv,
                                                 const ushort* __restrict__ vtb,
                                                 const float* __restrict__ sums,
                                                 ushort* __restrict__ op0,
                                                 ushort* __restrict__ op1) {
    __shared__ ushort Kbuf[2 * 4096];
    __shared__ ushort Vbuf[2 * 4096];
    __shared__ ushort P[4][16][40];  // single buffer: per-wave FIFO DS ordering makes dbuf unnecessary
    const int bid = blockIdx.x;
    const int strip = 127 - (bid >> 3);
    const int cs = (bid >> 2) & 1;
    const int hg = bid & 3;
    const int q0 = strip << 4;
    const int lane = threadIdx.x & 63, wid = threadIdx.x >> 6;
    const int h = hg * 4 + wid;
    const int l15 = lane & 15, lhi = lane >> 4;
    const int qrow = q0 + l15;
    const ushort* kb = qkv + 4096;

    bf16x8 q1f[4], q2f[4];
    {
        size_t base = (size_t)qrow * LDQ + h * 128 + lhi * 8;
#pragma unroll
        for (int c = 0; c < 4; ++c) {
            q1f[c] = *(const bf16x8*)(qkv + base + c * 32);
            q2f[c] = *(const bf16x8*)(qkv + base + 2048 + c * 32);
        }
    }

    const float sum1 = sums[(size_t)(0 * 16 + h) * 2048 + qrow] + sums[(size_t)(2 * 16 + h) * 2048 + qrow];
    const float sum2 = sums[(size_t)(1 * 16 + h) * 2048 + qrow] + sums[(size_t)(3 * 16 + h) * 2048 + qrow];
    const float inv_denom = 1.0f / (0.5f + 1e-8f);
    const float c1 = inv_denom / sum1;
    const float c2 = 0.5f * inv_denom / sum2;

    f32x4 o[8];
#pragma unroll
    for (int dt = 0; dt < 8; ++dt) o[dt] = (f32x4){0.f, 0.f, 0.f, 0.f};

    const int nchunk = (strip >> 1) + 1;
    const int ndiag = nchunk - 1;
    const int nch = (nchunk - cs + 1) >> 1;

    if (nch > 0) {
        stage_k_chunk(kb, cs * 32, Kbuf, wid, lane);
        stage_v_chunk(vtb, cs * 32, Vbuf, wid, lane);
    }
    __syncthreads();
    for (int i = 0; i < nch; ++i) {
        const int ch = cs + 2 * i, kc = ch << 5;
        if (i + 1 < nch) {
            stage_k_chunk(kb, kc + 64, Kbuf + ((i + 1) & 1) * 4096, wid, lane);
            stage_v_chunk(vtb, kc + 64, Vbuf + ((i + 1) & 1) * 4096, wid, lane);
        }
        const ushort* kcur = Kbuf + (i & 1) * 4096;
        const ushort* vcur = Vbuf + (i & 1) * 4096;
        ushort* Pb = &P[wid][0][0];
        if (ch == ndiag)
            pv_chunk<true>(kcur, vcur, kc, Pb, l15, lhi, qrow, q1f, q2f, c1, c2, o);
        else
            pv_chunk<false>(kcur, vcur, kc, Pb, l15, lhi, qrow, q1f, q2f, c1, c2, o);
        __syncthreads();
    }

    ushort* op = cs ? op1 : op0;
#pragma unroll
    for (int dt = 0; dt < 8; ++dt)
#pragma unroll
        for (int r = 0; r < 4; ++r)
            op[(size_t)(q0 + lhi * 4 + r) * 2048 + h * 128 + dt * 16 + l15] = f2bf(o[dt][r]);
}

// ---------------- combine partial O halves: aob = bf16(op0 + op1) ----------------
__device__ __forceinline__ unsigned int addbf2(unsigned int a, unsigned int b) {
    float alo = bf2f((ushort)a), ahi = bf2f((ushort)(a >> 16));
    float blo = bf2f((ushort)b), bhi = bf2f((ushort)(b >> 16));
    return (unsigned int)f2bf(alo + blo) | ((unsigned int)f2bf(ahi + bhi) << 16);
}
__global__ void combine_k(const ushort* __restrict__ o0, const ushort* __restrict__ o1,
                          ushort* __restrict__ out, int n8) {
    int i = blockIdx.x * blockDim.x + threadIdx.x;
    if (i >= n8) return;
    uint4 a = ((const uint4*)o0)[i];
    uint4 b = ((const uint4*)o1)[i];
    uint4 c;
    c.x = addbf2(a.x, b.x);
    c.y = addbf2(a.y, b.y);
    c.z = addbf2(a.z, b.z);
    c.w = addbf2(a.w, b.w);
    ((uint4*)out)[i] = c;
}

extern "C" void kernel_launch(void* const* d_in, const int* in_sizes, int n_in,
                              void* d_out, int out_size, void* d_ws, size_t ws_size,
                              hipStream_t stream) {
    const int S = 2048, HID = 2048;

    const float* x = (const float*)d_in[0];
    const float* fcos = (const float*)d_in[1];
    const float* fsin = (const float*)d_in[2];
    // d_in[3] = mask (causal, implicit)
    const float* q1w = (const float*)d_in[4];
    const float* q2w = (const float*)d_in[5];
    const float* kw = (const float*)d_in[6];
    const float* vw = (const float*)d_in[7];
    const float* ow = (const float*)d_in[8];

    ushort* xb = (ushort*)d_ws;                        // 8MB; reused as opart0
    ushort* btq = xb + (size_t)4194304;                // fused Bt: w1t|w2t|wkt|wvt (17MB)
    ushort* w1t = btq;                                 //   reused as opart1
    ushort* w2t = btq + (size_t)2048 * 2048;           //   reused as aob
    ushort* wkt = btq + (size_t)4096 * 2048;
    ushort* wvt = btq + (size_t)4224 * 2048;
    ushort* wot = btq + (size_t)8912896;               // 8MB
    ushort* qkvb = wot + (size_t)4194304;              // 17MB
    ushort* vtb = qkvb + (size_t)8912896;              // 0.5MB
    float* sums = (float*)(vtb + (size_t)262144);      // 0.5MB
    ushort* opart0 = xb;
    ushort* opart1 = w1t;
    ushort* aob = w2t;

    // 1. fused preprocessing: cvt(x) + 5 weight transpose/converts
    prep_k<<<dim3(16896), dim3(256), 0, stream>>>(x, xb, q1w, q2w, kw, vw, ow,
                                                  w1t, w2t, wkt, wvt, wot);

    // 2. fused QKV projection (K head-slot scaled by 1/sqrt(128)*log2e at col-tile 32)
    gemm_glds_k<<<dim3(544), dim3(256), 0, stream>>>(xb, HID, btq, HID, qkvb, LDQ, HID, 16, 1, 32);

    // 3. fused RoPE (q1|q2|k slots) + V -> Vt [128][2048]
    rope_vt_k<<<dim3(17152), dim3(256), 0, stream>>>(qkvb, fcos, fsin, vtb);

    // 4. attention pass 1 (exp2-sums)
    attn_sums_k<<<dim3(1024), dim3(256), 0, stream>>>(qkvb, sums);

    // 5. attention pass 2 (PV partials)
    attn_pv_k<<<dim3(1024), dim3(256), 0, stream>>>(qkvb, vtb, sums, opart0, opart1);

    // 6. combine halves -> aob
    combine_k<<<dim3(2048), dim3(256), 0, stream>>>(opart0, opart1, aob, S * HID / 8);

    // 7. output projection (f32 out)
    gemm_glds_k<<<dim3(256), dim3(256), 0, stream>>>(aob, HID, wot, HID, (float*)d_out, HID, HID, 16, 0, -1);
}

// Round 7
// 179.279 us; speedup vs baseline: 4.3190x; 1.0930x over previous
//
#include <hip/hip_runtime.h>
#include <hip/hip_bf16.h>

typedef __attribute__((ext_vector_type(8))) short bf16x8;
typedef __attribute__((ext_vector_type(4))) float f32x4;

#define MFMA16(a, b, c) __builtin_amdgcn_mfma_f32_16x16x32_bf16((a), (b), (c), 0, 0, 0)

#define LDQ 4352  // fused qkv row stride (2048+2048+128+128)
// K columns are pre-scaled by 1/sqrt(128)*log2(e) in the QKV GEMM epilogue,
// so attention probabilities are exp2(s) = v_exp_f32(s) directly.
#define KSCALE 0.12751743f

__device__ __forceinline__ ushort f2bf(float f) {
    unsigned int x = __float_as_uint(f);
    x += 0x7fffu + ((x >> 16) & 1u);
    return (ushort)(x >> 16);
}
__device__ __forceinline__ float bf2f(ushort u) {
    return __uint_as_float(((unsigned int)u) << 16);
}
__device__ __forceinline__ float exp2_fast(float x) {
    float r;
    asm("v_exp_f32 %0, %1" : "=v"(r) : "v"(x));
    return r;
}
__device__ __forceinline__ unsigned int cvtpk(float lo, float hi) {
    unsigned int r;
    asm("v_cvt_pk_bf16_f32 %0, %1, %2" : "=v"(r) : "v"(lo), "v"(hi));
    return r;
}

__device__ __forceinline__ void gload16(const ushort* g, ushort* l) {
    __builtin_amdgcn_global_load_lds((const __attribute__((address_space(1))) unsigned int*)g,
                                     (__attribute__((address_space(3))) unsigned int*)l, 16, 0, 0);
}

// ---------------- fused preprocessing: cvt(x) + 5 weight transposes ----------------
__global__ __launch_bounds__(256) void prep_k(const float* __restrict__ x, ushort* __restrict__ xb,
                                              const float* __restrict__ q1w, const float* __restrict__ q2w,
                                              const float* __restrict__ kw, const float* __restrict__ vw,
                                              const float* __restrict__ ow,
                                              ushort* __restrict__ w1t, ushort* __restrict__ w2t,
                                              ushort* __restrict__ wkt, ushort* __restrict__ wvt,
                                              ushort* __restrict__ wot) {
    int bid = blockIdx.x;
    if (bid < 4096) {
        int i = bid * 256 + threadIdx.x;
        float4 v = ((const float4*)x)[i];
        ushort4 u;
        u.x = f2bf(v.x); u.y = f2bf(v.y); u.z = f2bf(v.z); u.w = f2bf(v.w);
        ((ushort4*)xb)[i] = u;
        return;
    }
    bid -= 4096;
    const float* in;
    ushort* out;
    int C, TX;
    if (bid < 4096) { in = q1w; out = w1t; C = 2048; TX = 64; }
    else if (bid < 8192) { bid -= 4096; in = q2w; out = w2t; C = 2048; TX = 64; }
    else if (bid < 12288) { bid -= 8192; in = ow; out = wot; C = 2048; TX = 64; }
    else if (bid < 12544) { bid -= 12288; in = kw; out = wkt; C = 128; TX = 4; }
    else { bid -= 12544; in = vw; out = wvt; C = 128; TX = 4; }
    __shared__ ushort t[32][33];
    const int c0 = (bid % TX) * 32, r0 = (bid / TX) * 32;
    const int lx = threadIdx.x & 31, ly = threadIdx.x >> 5;
#pragma unroll
    for (int i = 0; i < 4; ++i)
        t[ly + i * 8][lx] = f2bf(in[(size_t)(r0 + ly + i * 8) * C + c0 + lx]);
    __syncthreads();
#pragma unroll
    for (int i = 0; i < 4; ++i)
        out[(size_t)(c0 + ly + i * 8) * 2048 + r0 + lx] = t[lx][ly + i * 8];
}

// ---------------- bf16 GEMM: 8 waves (2x4), 128x128 tile, dbuf global_load_lds ----------------
// Wave (wr,wc) computes rows wr*64+m*16, cols wc*16 + n*64 (n=0,1) -> RoPE pair (d,d+64)
// is wave-local. FUSE: tiles 0..32 -> rope (+KSCALE on 32) into qkv; tile 33 -> transposed V
// into vtb (acc rows contiguous in transposed layout -> packed 8B stores).
template <bool FUSE>
__global__ __launch_bounds__(512) void gemm8_k(const ushort* __restrict__ A, int lda,
                                               const ushort* __restrict__ Bt, int ldb,
                                               void* __restrict__ C, int ldc,
                                               int K, int nbx, int cbf,
                                               const float* __restrict__ cs,
                                               const float* __restrict__ sn,
                                               ushort* __restrict__ vtb) {
    __shared__ ushort As[2 * 4096];
    __shared__ ushort Bs[2 * 4096];
    const int tid = threadIdx.x;
    const int lane = tid & 63, wid = tid >> 6;
    const int cpx = (int)gridDim.x >> 3;
    const int swz = ((int)blockIdx.x & 7) * cpx + ((int)blockIdx.x >> 3);
    const int nt = swz / nbx;
    const int m0 = (swz % nbx) * 128, n0 = nt * 128;
    const int wr = wid >> 2, wc = wid & 3;
    const int l15 = lane & 15, lhi = lane >> 4;

    // staging: thread covers row tid>>2, 16B slot tid&3; source col pre-swizzled
    // (slot ^= (row>>1)&3); LDS dest linear [row][slot] (wave-uniform base + lane*16B).
    const int srow = tid >> 2;
    const int scol = (((tid & 3) ^ ((srow >> 1) & 3)) << 3);
    const ushort* gA = A + (size_t)(m0 + srow) * lda + scol;
    const ushort* gB = Bt + (size_t)(n0 + srow) * ldb + scol;
    ushort* lA = &As[wid * 512];
    ushort* lB = &Bs[wid * 512];

    f32x4 acc[4][2];
#pragma unroll
    for (int m = 0; m < 4; ++m)
#pragma unroll
        for (int n = 0; n < 2; ++n) acc[m][n] = (f32x4){0.f, 0.f, 0.f, 0.f};

    const int fcol = (lhi << 4) ^ (((l15 >> 1) & 3) << 4);

    gload16(gA, lA);
    gload16(gB, lB);
    __syncthreads();

    int cur = 0;
    for (int k0 = 0; k0 < K; k0 += 32) {
        if (k0 + 32 < K) {
            gload16(gA + k0 + 32, lA + (cur ^ 1) * 4096);
            gload16(gB + k0 + 32, lB + (cur ^ 1) * 4096);
        }
        const char* aB = (const char*)&As[cur * 4096];
        const char* bB = (const char*)&Bs[cur * 4096];
        bf16x8 af[4], bfr[2];
#pragma unroll
        for (int m = 0; m < 4; ++m)
            af[m] = *(const bf16x8*)(aB + (wr * 64 + m * 16 + l15) * 64 + fcol);
#pragma unroll
        for (int n = 0; n < 2; ++n)
            bfr[n] = *(const bf16x8*)(bB + (wc * 16 + n * 64 + l15) * 64 + fcol);
#pragma unroll
        for (int m = 0; m < 4; ++m)
#pragma unroll
            for (int n = 0; n < 2; ++n)
                acc[m][n] = MFMA16(af[m], bfr[n], acc[m][n]);
        __syncthreads();
        cur ^= 1;
    }

    if (FUSE) {
        if (nt == 33) {
            // V tile -> vtb[128][2048] (transposed); rows rb..rb+3 contiguous in vtb
#pragma unroll
            for (int m = 0; m < 4; ++m) {
                const int rb = m0 + wr * 64 + m * 16 + lhi * 4;
#pragma unroll
                for (int n = 0; n < 2; ++n) {
                    const int d = wc * 16 + n * 64 + l15;
                    uint2 w;
                    w.x = cvtpk(acc[m][n][0], acc[m][n][1]);
                    w.y = cvtpk(acc[m][n][2], acc[m][n][3]);
                    *(uint2*)(vtb + (size_t)d * 2048 + rb) = w;
                }
            }
        } else {
            const float scale = (nt == 32) ? KSCALE : 1.0f;
            ushort* out = (ushort*)C;
            const int d0 = wc * 16 + l15;
#pragma unroll
            for (int m = 0; m < 4; ++m) {
                const int rb = m0 + wr * 64 + m * 16 + lhi * 4;
#pragma unroll
                for (int r = 0; r < 4; ++r) {
                    const int row = rb + r;
                    float c0 = cs[row * 128 + d0], c1 = cs[row * 128 + d0 + 64];
                    float s0 = sn[row * 128 + d0], s1 = sn[row * 128 + d0 + 64];
                    float t0 = acc[m][0][r], t1 = acc[m][1][r];
                    out[(size_t)row * ldc + n0 + d0] = f2bf((t0 * c0 - t1 * s0) * scale);
                    out[(size_t)row * ldc + n0 + d0 + 64] = f2bf((t1 * c1 + t0 * s1) * scale);
                }
            }
        }
    } else {
#pragma unroll
        for (int m = 0; m < 4; ++m) {
            const int rb = m0 + wr * 64 + m * 16 + lhi * 4;
#pragma unroll
            for (int n = 0; n < 2; ++n) {
                const int col = n0 + wc * 16 + n * 64 + l15;
#pragma unroll
                for (int r = 0; r < 4; ++r) {
                    if (cbf)
                        ((ushort*)C)[(size_t)(rb + r) * ldc + col] = f2bf(acc[m][n][r]);
                    else
                        ((float*)C)[(size_t)(rb + r) * ldc + col] = acc[m][n][r];
                }
            }
        }
    }
}

// ---------------- differential MQA attention ----------------
// Blocks of 4 waves = 4 heads sharing one 16-row q-strip; K (and V) chunks staged
// once per block into double-buffered, XOR-swizzled LDS. K arrives pre-scaled so
// probabilities are exp2(s) directly (single v_exp_f32).

__device__ __forceinline__ void stage_k_chunk(const ushort* __restrict__ kb, int kc,
                                              ushort* __restrict__ kbuf, int wid, int lane) {
#pragma unroll
    for (int u = 0; u < 2; ++u) {
        const int w = wid * 2 + u;
        const int row = w * 4 + (lane >> 4);
        const int colb = ((lane & 15) * 16) ^ ((row & 7) << 4);
        gload16(kb + (size_t)(kc + row) * LDQ + (colb >> 1), kbuf + w * 512);
    }
}

__device__ __forceinline__ void stage_v_chunk(const ushort* __restrict__ vtb, int kc,
                                              ushort* __restrict__ vbuf, int wid, int lane) {
#pragma unroll
    for (int u = 0; u < 2; ++u) {
        const int w = wid * 2 + u;
        const int rowd = w * 16 + (lane >> 2);
        const int colb = ((lane & 3) * 16) ^ (((rowd >> 1) & 3) << 4);
        gload16(vtb + (size_t)rowd * 2048 + kc + (colb >> 1), vbuf + w * 512);
    }
}

__device__ __forceinline__ void load_k_frags(const ushort* __restrict__ kbuf, int l15, int lhi,
                                             bf16x8 kf[2][4]) {
    const char* kB = (const char*)kbuf;
#pragma unroll
    for (int n2 = 0; n2 < 2; ++n2) {
        const int r = n2 * 16 + l15;
#pragma unroll
        for (int c = 0; c < 4; ++c)
            kf[n2][c] = *(const bf16x8*)(kB + r * 256 + ((lhi * 16 + c * 64) ^ ((r & 7) << 4)));
    }
}

template <bool MASKED>
__device__ __forceinline__ void sums_chunk(const ushort* __restrict__ kbuf, int kc,
                                           int l15, int lhi, int qrow,
                                           const bf16x8* q1f, const bf16x8* q2f,
                                           float& sum1, float& sum2) {
    bf16x8 kf[2][4];
    load_k_frags(kbuf, l15, lhi, kf);
    f32x4 s1[2], s2[2];
#pragma unroll
    for (int n2 = 0; n2 < 2; ++n2) {
        s1[n2] = (f32x4){0.f, 0.f, 0.f, 0.f};
        s2[n2] = (f32x4){0.f, 0.f, 0.f, 0.f};
#pragma unroll
        for (int c = 0; c < 4; ++c) {
            s1[n2] = MFMA16(kf[n2][c], q1f[c], s1[n2]);
            s2[n2] = MFMA16(kf[n2][c], q2f[c], s2[n2]);
        }
    }
    const int kbase = kc + lhi * 4;
#pragma unroll
    for (int n2 = 0; n2 < 2; ++n2)
#pragma unroll
        for (int r = 0; r < 4; ++r) {
            float e1 = exp2_fast(s1[n2][r]);
            float e2 = exp2_fast(s2[n2][r]);
            if (MASKED) {
                bool ok = (kbase + n2 * 16 + r) <= qrow;
                e1 = ok ? e1 : 0.f;
                e2 = ok ? e2 : 0.f;
            }
            sum1 += e1;
            sum2 += e2;
        }
}

__global__ __launch_bounds__(256) void attn_sums_k(const ushort* __restrict__ qkv,
                                                   float* __restrict__ sums) {
    __shared__ ushort Kbuf[2 * 4096];
    const int bid = blockIdx.x;
    const int strip = 127 - (bid >> 3);  // longest-first
    const int cs = (bid >> 2) & 1;
    const int hg = bid & 3;
    const int q0 = strip << 4;
    const int lane = threadIdx.x & 63, wid = threadIdx.x >> 6;
    const int h = hg * 4 + wid;
    const int l15 = lane & 15, lhi = lane >> 4;
    const int qrow = q0 + l15;
    const ushort* kb = qkv + 4096;

    bf16x8 q1f[4], q2f[4];
    {
        size_t base = (size_t)qrow * LDQ + h * 128 + lhi * 8;
#pragma unroll
        for (int c = 0; c < 4; ++c) {
            q1f[c] = *(const bf16x8*)(qkv + base + c * 32);
            q2f[c] = *(const bf16x8*)(qkv + base + 2048 + c * 32);
        }
    }

    const int nchunk = (strip >> 1) + 1;
    const int ndiag = nchunk - 1;
    const int nch = (nchunk - cs + 1) >> 1;  // chunks with parity cs

    float sum1 = 0.f, sum2 = 0.f;
    if (nch > 0) stage_k_chunk(kb, cs * 32, Kbuf, wid, lane);
    __syncthreads();
    for (int i = 0; i < nch; ++i) {
        const int ch = cs + 2 * i, kc = ch << 5;
        if (i + 1 < nch) stage_k_chunk(kb, kc + 64, Kbuf + ((i + 1) & 1) * 4096, wid, lane);
        const ushort* kcur = Kbuf + (i & 1) * 4096;
        if (ch == ndiag)
            sums_chunk<true>(kcur, kc, l15, lhi, qrow, q1f, q2f, sum1, sum2);
        else
            sums_chunk<false>(kcur, kc, l15, lhi, qrow, q1f, q2f, sum1, sum2);
        __syncthreads();
    }

    sum1 += __shfl_xor(sum1, 16);
    sum1 += __shfl_xor(sum1, 32);
    sum2 += __shfl_xor(sum2, 16);
    sum2 += __shfl_xor(sum2, 32);

    if (lhi == 0) {
        sums[(size_t)((cs * 2 + 0) * 16 + h) * 2048 + qrow] = sum1;
        sums[(size_t)((cs * 2 + 1) * 16 + h) * 2048 + qrow] = sum2;
    }
}

template <bool MASKED>
__device__ __forceinline__ void pv_chunk(const ushort* __restrict__ kbuf, const ushort* __restrict__ vbuf,
                                         int kc, ushort* __restrict__ Pb,
                                         int l15, int lhi, int qrow,
                                         const bf16x8* q1f, const bf16x8* q2f,
                                         float c1, float c2, f32x4* o) {
    bf16x8 kf[2][4];
    load_k_frags(kbuf, l15, lhi, kf);
    bf16x8 vf[8];
    const char* vB = (const char*)vbuf;
#pragma unroll
    for (int dt = 0; dt < 8; ++dt) {
        const int d = dt * 16 + l15;
        vf[dt] = *(const bf16x8*)(vB + d * 64 + ((lhi * 16) ^ (((d >> 1) & 3) << 4)));
    }
    f32x4 s1[2], s2[2];
#pragma unroll
    for (int n2 = 0; n2 < 2; ++n2) {
        s1[n2] = (f32x4){0.f, 0.f, 0.f, 0.f};
        s2[n2] = (f32x4){0.f, 0.f, 0.f, 0.f};
#pragma unroll
        for (int c = 0; c < 4; ++c) {
            s1[n2] = MFMA16(kf[n2][c], q1f[c], s1[n2]);
            s2[n2] = MFMA16(kf[n2][c], q2f[c], s2[n2]);
        }
    }
    const int kbase = kc + lhi * 4;
#pragma unroll
    for (int n2 = 0; n2 < 2; ++n2) {
        float p[4];
#pragma unroll
        for (int r = 0; r < 4; ++r) {
            float e1 = exp2_fast(s1[n2][r]) * c1;
            float e2 = exp2_fast(s2[n2][r]) * c2;
            float pv = fmaxf(e1 - e2, 0.f);
            if (MASKED) pv = ((kbase + n2 * 16 + r) <= qrow) ? pv : 0.f;
            p[r] = pv;
        }
        uint2 w;
        w.x = cvtpk(p[0], p[1]);
        w.y = cvtpk(p[2], p[3]);
        *(uint2*)(Pb + l15 * 40 + n2 * 16 + lhi * 4) = w;
    }
    // per-wave private P region; same-wave DS ops are FIFO -> only lgkm drain needed
    asm volatile("s_waitcnt lgkmcnt(0)" ::: "memory");
    bf16x8 pf = *(const bf16x8*)(Pb + l15 * 40 + lhi * 8);
#pragma unroll
    for (int dt = 0; dt < 8; ++dt)
        o[dt] = MFMA16(pf, vf[dt], o[dt]);
}

__global__ __launch_bounds__(256) void attn_pv_k(const ushort* __restrict__ qkv,
                                                 const ushort* __restrict__ vtb,
                                                 const float* __restrict__ sums,
                                                 ushort* __restrict__ op0,
                                                 ushort* __restrict__ op1) {
    __shared__ ushort Kbuf[2 * 4096];
    __shared__ ushort Vbuf[2 * 4096];
    __shared__ ushort P[4][16][40];
    const int bid = blockIdx.x;
    const int strip = 127 - (bid >> 3);
    const int cs = (bid >> 2) & 1;
    const int hg = bid & 3;
    const int q0 = strip << 4;
    const int lane = threadIdx.x & 63, wid = threadIdx.x >> 6;
    const int h = hg * 4 + wid;
    const int l15 = lane & 15, lhi = lane >> 4;
    const int qrow = q0 + l15;
    const ushort* kb = qkv + 4096;

    bf16x8 q1f[4], q2f[4];
    {
        size_t base = (size_t)qrow * LDQ + h * 128 + lhi * 8;
#pragma unroll
        for (int c = 0; c < 4; ++c) {
            q1f[c] = *(const bf16x8*)(qkv + base + c * 32);
            q2f[c] = *(const bf16x8*)(qkv + base + 2048 + c * 32);
        }
    }

    const float sum1 = sums[(size_t)(0 * 16 + h) * 2048 + qrow] + sums[(size_t)(2 * 16 + h) * 2048 + qrow];
    const float sum2 = sums[(size_t)(1 * 16 + h) * 2048 + qrow] + sums[(size_t)(3 * 16 + h) * 2048 + qrow];
    const float inv_denom = 1.0f / (0.5f + 1e-8f);
    const float c1 = inv_denom / sum1;
    const float c2 = 0.5f * inv_denom / sum2;

    f32x4 o[8];
#pragma unroll
    for (int dt = 0; dt < 8; ++dt) o[dt] = (f32x4){0.f, 0.f, 0.f, 0.f};

    const int nchunk = (strip >> 1) + 1;
    const int ndiag = nchunk - 1;
    const int nch = (nchunk - cs + 1) >> 1;

    if (nch > 0) {
        stage_k_chunk(kb, cs * 32, Kbuf, wid, lane);
        stage_v_chunk(vtb, cs * 32, Vbuf, wid, lane);
    }
    __syncthreads();
    for (int i = 0; i < nch; ++i) {
        const int ch = cs + 2 * i, kc = ch << 5;
        if (i + 1 < nch) {
            stage_k_chunk(kb, kc + 64, Kbuf + ((i + 1) & 1) * 4096, wid, lane);
            stage_v_chunk(vtb, kc + 64, Vbuf + ((i + 1) & 1) * 4096, wid, lane);
        }
        const ushort* kcur = Kbuf + (i & 1) * 4096;
        const ushort* vcur = Vbuf + (i & 1) * 4096;
        ushort* Pb = &P[wid][0][0];
        if (ch == ndiag)
            pv_chunk<true>(kcur, vcur, kc, Pb, l15, lhi, qrow, q1f, q2f, c1, c2, o);
        else
            pv_chunk<false>(kcur, vcur, kc, Pb, l15, lhi, qrow, q1f, q2f, c1, c2, o);
        __syncthreads();
    }

    ushort* op = cs ? op1 : op0;
#pragma unroll
    for (int dt = 0; dt < 8; ++dt)
#pragma unroll
        for (int r = 0; r < 4; ++r)
            op[(size_t)(q0 + lhi * 4 + r) * 2048 + h * 128 + dt * 16 + l15] = f2bf(o[dt][r]);
}

// ---------------- combine partial O halves: aob = bf16(op0 + op1) ----------------
__device__ __forceinline__ unsigned int addbf2(unsigned int a, unsigned int b) {
    float alo = bf2f((ushort)a), ahi = bf2f((ushort)(a >> 16));
    float blo = bf2f((ushort)b), bhi = bf2f((ushort)(b >> 16));
    return (unsigned int)f2bf(alo + blo) | ((unsigned int)f2bf(ahi + bhi) << 16);
}
__global__ void combine_k(const ushort* __restrict__ o0, const ushort* __restrict__ o1,
                          ushort* __restrict__ out, int n8) {
    int i = blockIdx.x * blockDim.x + threadIdx.x;
    if (i >= n8) return;
    uint4 a = ((const uint4*)o0)[i];
    uint4 b = ((const uint4*)o1)[i];
    uint4 c;
    c.x = addbf2(a.x, b.x);
    c.y = addbf2(a.y, b.y);
    c.z = addbf2(a.z, b.z);
    c.w = addbf2(a.w, b.w);
    ((uint4*)out)[i] = c;
}

extern "C" void kernel_launch(void* const* d_in, const int* in_sizes, int n_in,
                              void* d_out, int out_size, void* d_ws, size_t ws_size,
                              hipStream_t stream) {
    const int S = 2048, HID = 2048;

    const float* x = (const float*)d_in[0];
    const float* fcos = (const float*)d_in[1];
    const float* fsin = (const float*)d_in[2];
    // d_in[3] = mask (causal, implicit)
    const float* q1w = (const float*)d_in[4];
    const float* q2w = (const float*)d_in[5];
    const float* kw = (const float*)d_in[6];
    const float* vw = (const float*)d_in[7];
    const float* ow = (const float*)d_in[8];

    ushort* xb = (ushort*)d_ws;                        // 8MB; reused as opart0
    ushort* btq = xb + (size_t)4194304;                // fused Bt: w1t|w2t|wkt|wvt (17MB)
    ushort* w1t = btq;                                 //   reused as opart1
    ushort* w2t = btq + (size_t)2048 * 2048;           //   reused as aob
    ushort* wkt = btq + (size_t)4096 * 2048;
    ushort* wvt = btq + (size_t)4224 * 2048;
    ushort* wot = btq + (size_t)8912896;               // 8MB
    ushort* qkvb = wot + (size_t)4194304;              // 17MB
    ushort* vtb = qkvb + (size_t)8912896;              // 0.5MB
    float* sums = (float*)(vtb + (size_t)262144);      // 0.5MB
    ushort* opart0 = xb;
    ushort* opart1 = w1t;
    ushort* aob = w2t;

    // 1. fused preprocessing: cvt(x) + 5 weight transpose/converts
    prep_k<<<dim3(16896), dim3(256), 0, stream>>>(x, xb, q1w, q2w, kw, vw, ow,
                                                  w1t, w2t, wkt, wvt, wot);

    // 2. fused QKV projection + RoPE + KSCALE + V-transpose (epilogue-fused)
    gemm8_k<true><<<dim3(544), dim3(512), 0, stream>>>(xb, HID, btq, HID, qkvb, LDQ, HID, 16, 1,
                                                       fcos, fsin, vtb);

    // 3. attention pass 1 (exp2-sums)
    attn_sums_k<<<dim3(1024), dim3(256), 0, stream>>>(qkvb, sums);

    // 4. attention pass 2 (PV partials)
    attn_pv_k<<<dim3(1024), dim3(256), 0, stream>>>(qkvb, vtb, sums, opart0, opart1);

    // 5. combine halves -> aob
    combine_k<<<dim3(2048), dim3(256), 0, stream>>>(opart0, opart1, aob, S * HID / 8);

    // 6. output projection (f32 out)
    gemm8_k<false><<<dim3(256), dim3(512), 0, stream>>>(aob, HID, wot, HID, (float*)d_out, HID, HID, 16, 0,
                                                        nullptr, nullptr, nullptr);
}